// Round 10
// baseline (223.281 us; speedup 1.0000x reference)
//
#include <hip/hip_runtime.h>
#include <math.h>

#define NB 512
#define LONGN 1000
#define SHORTN 50
#define TOPKN 50
#define HALFN 500
#define NG 8          // item-groups per hard block
#define EROW 72       // hard-path bf16 LDS row stride (shorts)
#define BROW 72       // bst bf16 row stride (shorts) for xbf/obf
#define F1ROW 136     // bst bf16 row stride for ff1 output (128+8)

typedef __attribute__((ext_vector_type(8))) short bf16x8;
typedef __attribute__((ext_vector_type(4))) float f32x4;

__device__ __forceinline__ float dot4(float4 a, float4 b) {
  return a.x*b.x + a.y*b.y + a.z*b.z + a.w*b.w;
}

template<int N>
__device__ __forceinline__ float dotN(const float* w, const float* x) {
  const float4* w4 = (const float4*)w;
  const float4* x4 = (const float4*)x;
  float a0 = 0.f, a1 = 0.f, a2 = 0.f, a3 = 0.f;
  #pragma unroll
  for (int k = 0; k < N/4; k += 4) {
    a0 += dot4(w4[k],   x4[k]);
    a1 += dot4(w4[k+1], x4[k+1]);
    a2 += dot4(w4[k+2], x4[k+2]);
    a3 += dot4(w4[k+3], x4[k+3]);
  }
  return (a0 + a1) + (a2 + a3);
}

__device__ __forceinline__ float wave_sum(float v) {
  #pragma unroll
  for (int off = 32; off > 0; off >>= 1) v += __shfl_xor(v, off);
  return v;
}
__device__ __forceinline__ float wave_max(float v) {
  #pragma unroll
  for (int off = 32; off > 0; off >>= 1) v = fmaxf(v, __shfl_xor(v, off));
  return v;
}

__device__ __forceinline__ unsigned short f2bf(float x) {  // RNE fp32->bf16
  unsigned u = __float_as_uint(x);
  return (unsigned short)((u + 0x7fffu + ((u >> 16) & 1u)) >> 16);
}

// ---------------- shared-memory layouts (union via dynamic LDS) ----------------
struct __align__(16) HardSM {
  short Abf[64*EROW];        // 9216 B
  short Ebuf[2][64*EROW];    // 18432 B
  float tv[64];
  float te[64];
  float2 cw[64];
  int idsL[HALFN];
  float redE[4*64];
};
struct __align__(16) BstSM {
  float xf[SHORTN*64];       // 12800
  short xbf[64*BROW];        // 9216
  float qf[SHORTN*68];       // 13600
  float arena[SHORTN*132];   // 26400
  short obf[64*BROW];        // 9216
};

// ===========================================================================
// hard-scores path (one block = 500 items of one batch row), R9 code.
// ===========================================================================
__device__ void hard_scores_path(
    const int bid, HardSM* S,
    const int* __restrict__ target_item_id,
    const int* __restrict__ long_hist_ids,
    const float* __restrict__ item_emb,
    const float* __restrict__ tproj_w, const float* __restrict__ tproj_b,
    const float* __restrict__ attn_w1, const float* __restrict__ attn_b1,
    const float* __restrict__ attn_w2, const float* __restrict__ attn_b2,
    const float* __restrict__ hash_emb,
    float* __restrict__ scores_ws, float* __restrict__ partA,
    float* __restrict__ partH)
{
  const int b = bid >> 1, half = bid & 1;
  const int base = half * HALFN;
  const int tid = threadIdx.x;
  const int wid = tid >> 6, lane = tid & 63;

  if (tid < 64) S->tv[tid] = item_emb[target_item_id[b]*64 + tid];
  for (int l = tid; l < HALFN; l += 256) S->idsL[l] = long_hist_ids[b*LONGN + base + l];
  __syncthreads();
  if (tid < 64) S->te[tid] = tproj_b[tid] + dotN<64>(tproj_w + tid*64, S->tv);
  __syncthreads();
  if (tid < 64) {
    float c = attn_b1[tid] + dotN<64>(attn_w1 + tid*192, S->te);
    S->cw[tid] = make_float2(c, attn_w2[tid]);
  }
  for (int idx = tid; idx < 4096; idx += 256) {
    int i = idx >> 6, j = idx & 63;
    S->Abf[i*EROW + j] = (short)f2bf(attn_w1[i*192 + 64 + j] + attn_w1[i*192 + 128 + j]*S->te[j]);
  }
  __syncthreads();

  bf16x8 a00,a01,a10,a11,a20,a21,a30,a31;
  {
    const short* ap = S->Abf + (lane & 15)*EROW + ((lane >> 4) << 3);
    a00 = *(const bf16x8*)(ap +  0*EROW);  a01 = *(const bf16x8*)(ap +  0*EROW + 32);
    a10 = *(const bf16x8*)(ap + 16*EROW);  a11 = *(const bf16x8*)(ap + 16*EROW + 32);
    a20 = *(const bf16x8*)(ap + 32*EROW);  a21 = *(const bf16x8*)(ap + 32*EROW + 32);
    a30 = *(const bf16x8*)(ap + 48*EROW);  a31 = *(const bf16x8*)(ap + 48*EROW + 32);
  }

  const float b2s = attn_b2[0];
  const int it_g = tid >> 2;
  const int dimg = (tid & 3) * 16;

  float4 sE0 = {0,0,0,0}, sE1 = {0,0,0,0}, sE2 = {0,0,0,0}, sE3 = {0,0,0,0};

  {
    const float4* ep = (const float4*)(item_emb + (size_t)S->idsL[it_g]*64 + dimg);
    float4 r0 = ep[0], r1 = ep[1], r2 = ep[2], r3 = ep[3];
    sE0.x+=r0.x; sE0.y+=r0.y; sE0.z+=r0.z; sE0.w+=r0.w;
    sE1.x+=r1.x; sE1.y+=r1.y; sE1.z+=r1.z; sE1.w+=r1.w;
    sE2.x+=r2.x; sE2.y+=r2.y; sE2.z+=r2.z; sE2.w+=r2.w;
    sE3.x+=r3.x; sE3.y+=r3.y; sE3.z+=r3.z; sE3.w+=r3.w;
    bf16x8 w0, w1;
    w0[0]=(short)f2bf(r0.x); w0[1]=(short)f2bf(r0.y); w0[2]=(short)f2bf(r0.z); w0[3]=(short)f2bf(r0.w);
    w0[4]=(short)f2bf(r1.x); w0[5]=(short)f2bf(r1.y); w0[6]=(short)f2bf(r1.z); w0[7]=(short)f2bf(r1.w);
    w1[0]=(short)f2bf(r2.x); w1[1]=(short)f2bf(r2.y); w1[2]=(short)f2bf(r2.z); w1[3]=(short)f2bf(r2.w);
    w1[4]=(short)f2bf(r3.x); w1[5]=(short)f2bf(r3.y); w1[6]=(short)f2bf(r3.z); w1[7]=(short)f2bf(r3.w);
    short* dst = &S->Ebuf[0][it_g*EROW + dimg];
    *(bf16x8*)dst = w0;  *(bf16x8*)(dst + 8) = w1;
  }
  __syncthreads();

  int buf = 0;
  for (int g = 0; g < NG; ++g) {
    float4 r0={0,0,0,0}, r1={0,0,0,0}, r2={0,0,0,0}, r3={0,0,0,0};
    const bool more = (g + 1 < NG);
    if (more) {
      const int gi = (g+1)*64 + it_g;
      if (gi < HALFN) {
        const float4* ep = (const float4*)(item_emb + (size_t)S->idsL[gi]*64 + dimg);
        r0 = ep[0]; r1 = ep[1]; r2 = ep[2]; r3 = ep[3];
      }
    }

    f32x4 acc0={0,0,0,0}, acc1={0,0,0,0}, acc2={0,0,0,0}, acc3={0,0,0,0};
    {
      const short* ep = &S->Ebuf[buf][(wid*16 + (lane & 15))*EROW + ((lane >> 4) << 3)];
      bf16x8 b0 = *(const bf16x8*)(ep);
      bf16x8 b1 = *(const bf16x8*)(ep + 32);
      acc0 = __builtin_amdgcn_mfma_f32_16x16x32_bf16(a00, b0, acc0, 0, 0, 0);
      acc0 = __builtin_amdgcn_mfma_f32_16x16x32_bf16(a01, b1, acc0, 0, 0, 0);
      acc1 = __builtin_amdgcn_mfma_f32_16x16x32_bf16(a10, b0, acc1, 0, 0, 0);
      acc1 = __builtin_amdgcn_mfma_f32_16x16x32_bf16(a11, b1, acc1, 0, 0, 0);
      acc2 = __builtin_amdgcn_mfma_f32_16x16x32_bf16(a20, b0, acc2, 0, 0, 0);
      acc2 = __builtin_amdgcn_mfma_f32_16x16x32_bf16(a21, b1, acc2, 0, 0, 0);
      acc3 = __builtin_amdgcn_mfma_f32_16x16x32_bf16(a30, b0, acc3, 0, 0, 0);
      acc3 = __builtin_amdgcn_mfma_f32_16x16x32_bf16(a31, b1, acc3, 0, 0, 0);
    }
    float p = 0.f;
    {
      const int rbase = (lane >> 4) << 2;
      #pragma unroll
      for (int r = 0; r < 4; ++r) {
        float2 c0 = S->cw[ 0 + rbase + r];
        float2 c1 = S->cw[16 + rbase + r];
        float2 c2 = S->cw[32 + rbase + r];
        float2 c3 = S->cw[48 + rbase + r];
        p += c0.y * fmaxf(acc0[r] + c0.x, 0.f);
        p += c1.y * fmaxf(acc1[r] + c1.x, 0.f);
        p += c2.y * fmaxf(acc2[r] + c2.x, 0.f);
        p += c3.y * fmaxf(acc3[r] + c3.x, 0.f);
      }
    }
    p += __shfl_xor(p, 16);
    p += __shfl_xor(p, 32);
    if (lane < 16) {
      const int gi = g*64 + wid*16 + lane;
      if (gi < HALFN) scores_ws[b*LONGN + base + gi] = b2s + p;
    }

    if (more) {
      sE0.x+=r0.x; sE0.y+=r0.y; sE0.z+=r0.z; sE0.w+=r0.w;
      sE1.x+=r1.x; sE1.y+=r1.y; sE1.z+=r1.z; sE1.w+=r1.w;
      sE2.x+=r2.x; sE2.y+=r2.y; sE2.z+=r2.z; sE2.w+=r2.w;
      sE3.x+=r3.x; sE3.y+=r3.y; sE3.z+=r3.z; sE3.w+=r3.w;
      bf16x8 w0, w1;
      w0[0]=(short)f2bf(r0.x); w0[1]=(short)f2bf(r0.y); w0[2]=(short)f2bf(r0.z); w0[3]=(short)f2bf(r0.w);
      w0[4]=(short)f2bf(r1.x); w0[5]=(short)f2bf(r1.y); w0[6]=(short)f2bf(r1.z); w0[7]=(short)f2bf(r1.w);
      w1[0]=(short)f2bf(r2.x); w1[1]=(short)f2bf(r2.y); w1[2]=(short)f2bf(r2.z); w1[3]=(short)f2bf(r2.w);
      w1[4]=(short)f2bf(r3.x); w1[5]=(short)f2bf(r3.y); w1[6]=(short)f2bf(r3.z); w1[7]=(short)f2bf(r3.w);
      short* dst = &S->Ebuf[buf ^ 1][it_g*EROW + dimg];
      *(bf16x8*)dst = w0;  *(bf16x8*)(dst + 8) = w1;
    }
    __syncthreads();
    buf ^= 1;
  }

  {
    float* red = (float*)&S->Ebuf[0][0];
    const int b17 = tid * 17;
    red[b17+ 0]=sE0.x; red[b17+ 1]=sE0.y; red[b17+ 2]=sE0.z; red[b17+ 3]=sE0.w;
    red[b17+ 4]=sE1.x; red[b17+ 5]=sE1.y; red[b17+ 6]=sE1.z; red[b17+ 7]=sE1.w;
    red[b17+ 8]=sE2.x; red[b17+ 9]=sE2.y; red[b17+10]=sE2.z; red[b17+11]=sE2.w;
    red[b17+12]=sE3.x; red[b17+13]=sE3.y; red[b17+14]=sE3.z; red[b17+15]=sE3.w;
    __syncthreads();
    if (tid < 64) {
      const int dg = tid >> 4, dw = tid & 15;
      float s = 0.f;
      for (int j = 0; j < 64; ++j) s += red[(j*4 + dg)*17 + dw];
      partA[bid*64 + tid] = s;
    }
  }

  {
    const int hl = lane >> 4, dd = lane & 15;
    const float* hb = hash_emb + hl*1024*16 + dd;
    float accH = 0.f;
    for (int l = wid; l < HALFN; l += 4)
      accH += hb[(S->idsL[l] & 1023)*16];
    S->redE[wid*64 + lane] = accH;
  }
  __syncthreads();
  if (wid == 0)
    partH[bid*64 + lane] = S->redE[lane] + S->redE[64+lane] + S->redE[128+lane] + S->redE[192+lane];
}

// ===========================================================================
// BST path (one block = one batch row), R9 MFMA code.
// ===========================================================================
__device__ void bst_path(
    const int b, BstSM* S,
    const int* __restrict__ short_ids, const float* __restrict__ item_emb,
    const short* __restrict__ wF,
    const float* __restrict__ qkv_b, const float* __restrict__ out_b,
    const float* __restrict__ ln1_g, const float* __restrict__ ln1_b,
    const float* __restrict__ ff1_b, const float* __restrict__ ff2_b,
    const float* __restrict__ ln2_g, const float* __restrict__ ln2_b,
    float* __restrict__ bst_out)
{
  float* xf    = S->xf;
  short* xbf   = S->xbf;
  float* qf    = S->qf;
  float* arena = S->arena;
  short* obf   = S->obf;
  short* f1bf  = (short*)arena;

  const int tid = threadIdx.x;
  const int wid = tid >> 6, lane = tid & 63;
  const int n16 = lane & 15;
  const int kg8 = (lane >> 4) << 3;
  const int mrow = (lane >> 4) << 2;

  for (int idx = tid; idx < SHORTN*64; idx += 256) {
    int s = idx >> 6, j = idx & 63;
    float v = item_emb[short_ids[b*SHORTN + s]*64 + j];
    xf[idx] = v;
    xbf[s*BROW + j] = (short)f2bf(v);
  }
  for (int idx = tid; idx < 14*BROW; idx += 256) {
    xbf[50*BROW + idx] = 0;
    obf[50*BROW + idx] = 0;
  }
  __syncthreads();

  for (int l = 0; l < 2; ++l) {
    // ======== qkv ========
    {
      const short* ap = xbf + n16*BROW + kg8;
      bf16x8 A00 = *(const bf16x8*)(ap);            bf16x8 A01 = *(const bf16x8*)(ap + 32);
      bf16x8 A10 = *(const bf16x8*)(ap + 16*BROW);  bf16x8 A11 = *(const bf16x8*)(ap + 16*BROW + 32);
      bf16x8 A20 = *(const bf16x8*)(ap + 32*BROW);  bf16x8 A21 = *(const bf16x8*)(ap + 32*BROW + 32);
      bf16x8 A30 = *(const bf16x8*)(ap + 48*BROW);  bf16x8 A31 = *(const bf16x8*)(ap + 48*BROW + 32);
      #pragma unroll
      for (int t = 0; t < 3; ++t) {
        const int nt = wid*3 + t;
        const short* bp = wF + (size_t)(l*24 + nt*2)*512 + lane*8;
        bf16x8 B0 = *(const bf16x8*)(bp);
        bf16x8 B1 = *(const bf16x8*)(bp + 512);
        f32x4 c0={0,0,0,0}, c1={0,0,0,0}, c2={0,0,0,0}, c3={0,0,0,0};
        c0 = __builtin_amdgcn_mfma_f32_16x16x32_bf16(A00, B0, c0, 0,0,0);
        c0 = __builtin_amdgcn_mfma_f32_16x16x32_bf16(A01, B1, c0, 0,0,0);
        c1 = __builtin_amdgcn_mfma_f32_16x16x32_bf16(A10, B0, c1, 0,0,0);
        c1 = __builtin_amdgcn_mfma_f32_16x16x32_bf16(A11, B1, c1, 0,0,0);
        c2 = __builtin_amdgcn_mfma_f32_16x16x32_bf16(A20, B0, c2, 0,0,0);
        c2 = __builtin_amdgcn_mfma_f32_16x16x32_bf16(A21, B1, c2, 0,0,0);
        c3 = __builtin_amdgcn_mfma_f32_16x16x32_bf16(A30, B0, c3, 0,0,0);
        c3 = __builtin_amdgcn_mfma_f32_16x16x32_bf16(A31, B1, c3, 0,0,0);
        const int c = nt*16 + n16;
        const float bias = qkv_b[l*192 + c];
        #pragma unroll
        for (int r = 0; r < 4; ++r) {
          int m0 = mrow + r;
          float v0 = c0[r] + bias;
          float v1 = c1[r] + bias;
          float v2 = c2[r] + bias;
          float v3 = c3[r] + bias;
          if (c < 64) {
            qf[m0*68 + c] = v0;
            if (m0+16 < SHORTN) qf[(m0+16)*68 + c] = v1;
            if (m0+32 < SHORTN) qf[(m0+32)*68 + c] = v2;
            if (m0+48 < SHORTN) qf[(m0+48)*68 + c] = v3;
          } else {
            const int cc = c - 64;
            arena[m0*132 + cc] = v0;
            if (m0+16 < SHORTN) arena[(m0+16)*132 + cc] = v1;
            if (m0+32 < SHORTN) arena[(m0+32)*132 + cc] = v2;
            if (m0+48 < SHORTN) arena[(m0+48)*132 + cc] = v3;
          }
        }
      }
    }
    __syncthreads();

    // ======== attention: f32 online softmax ========
    if (tid < 4*SHORTN) {
      const int h = tid / SHORTN, s = tid - h*SHORTN;
      const float4* qp = (const float4*)(qf + s*68 + h*16);
      const float4 qA = qp[0], qB2 = qp[1], qC = qp[2], qD = qp[3];
      float m = -INFINITY, ss = 0.f;
      float4 oa0 = {0,0,0,0}, oa1 = {0,0,0,0}, oa2 = {0,0,0,0}, oa3 = {0,0,0,0};
      for (int t2 = 0; t2 < SHORTN; ++t2) {
        const float4* kp = (const float4*)(arena + t2*132 + h*16);
        float d = dot4(qA,kp[0]) + dot4(qB2,kp[1]) + dot4(qC,kp[2]) + dot4(qD,kp[3]);
        d *= 0.25f;
        float mn = fmaxf(m, d);
        float al = __expf(m - mn);
        float a  = __expf(d - mn);
        m = mn;
        ss = ss*al + a;
        const float4* vp = (const float4*)(arena + t2*132 + 64 + h*16);
        float4 v0 = vp[0], v1 = vp[1], v2 = vp[2], v3 = vp[3];
        oa0.x = oa0.x*al + a*v0.x; oa0.y = oa0.y*al + a*v0.y;
        oa0.z = oa0.z*al + a*v0.z; oa0.w = oa0.w*al + a*v0.w;
        oa1.x = oa1.x*al + a*v1.x; oa1.y = oa1.y*al + a*v1.y;
        oa1.z = oa1.z*al + a*v1.z; oa1.w = oa1.w*al + a*v1.w;
        oa2.x = oa2.x*al + a*v2.x; oa2.y = oa2.y*al + a*v2.y;
        oa2.z = oa2.z*al + a*v2.z; oa2.w = oa2.w*al + a*v2.w;
        oa3.x = oa3.x*al + a*v3.x; oa3.y = oa3.y*al + a*v3.y;
        oa3.z = oa3.z*al + a*v3.z; oa3.w = oa3.w*al + a*v3.w;
      }
      const float inv = 1.f/ss;
      bf16x8 w0, w1;
      w0[0]=(short)f2bf(oa0.x*inv); w0[1]=(short)f2bf(oa0.y*inv);
      w0[2]=(short)f2bf(oa0.z*inv); w0[3]=(short)f2bf(oa0.w*inv);
      w0[4]=(short)f2bf(oa1.x*inv); w0[5]=(short)f2bf(oa1.y*inv);
      w0[6]=(short)f2bf(oa1.z*inv); w0[7]=(short)f2bf(oa1.w*inv);
      w1[0]=(short)f2bf(oa2.x*inv); w1[1]=(short)f2bf(oa2.y*inv);
      w1[2]=(short)f2bf(oa2.z*inv); w1[3]=(short)f2bf(oa2.w*inv);
      w1[4]=(short)f2bf(oa3.x*inv); w1[5]=(short)f2bf(oa3.y*inv);
      w1[6]=(short)f2bf(oa3.z*inv); w1[7]=(short)f2bf(oa3.w*inv);
      short* op = obf + s*BROW + h*16;
      *(bf16x8*)op = w0;  *(bf16x8*)(op + 8) = w1;
    }
    __syncthreads();

    // ======== out-proj + y ========
    {
      const short* ap = obf + n16*BROW + kg8;
      bf16x8 A00 = *(const bf16x8*)(ap);            bf16x8 A01 = *(const bf16x8*)(ap + 32);
      bf16x8 A10 = *(const bf16x8*)(ap + 16*BROW);  bf16x8 A11 = *(const bf16x8*)(ap + 16*BROW + 32);
      bf16x8 A20 = *(const bf16x8*)(ap + 32*BROW);  bf16x8 A21 = *(const bf16x8*)(ap + 32*BROW + 32);
      bf16x8 A30 = *(const bf16x8*)(ap + 48*BROW);  bf16x8 A31 = *(const bf16x8*)(ap + 48*BROW + 32);
      const int nt = wid;
      const short* bp = wF + (size_t)(48 + l*8 + nt*2)*512 + lane*8;
      bf16x8 B0 = *(const bf16x8*)(bp);
      bf16x8 B1 = *(const bf16x8*)(bp + 512);
      f32x4 c0={0,0,0,0}, c1={0,0,0,0}, c2={0,0,0,0}, c3={0,0,0,0};
      c0 = __builtin_amdgcn_mfma_f32_16x16x32_bf16(A00, B0, c0, 0,0,0);
      c0 = __builtin_amdgcn_mfma_f32_16x16x32_bf16(A01, B1, c0, 0,0,0);
      c1 = __builtin_amdgcn_mfma_f32_16x16x32_bf16(A10, B0, c1, 0,0,0);
      c1 = __builtin_amdgcn_mfma_f32_16x16x32_bf16(A11, B1, c1, 0,0,0);
      c2 = __builtin_amdgcn_mfma_f32_16x16x32_bf16(A20, B0, c2, 0,0,0);
      c2 = __builtin_amdgcn_mfma_f32_16x16x32_bf16(A21, B1, c2, 0,0,0);
      c3 = __builtin_amdgcn_mfma_f32_16x16x32_bf16(A30, B0, c3, 0,0,0);
      c3 = __builtin_amdgcn_mfma_f32_16x16x32_bf16(A31, B1, c3, 0,0,0);
      const int c = nt*16 + n16;
      const float bias = out_b[l*64 + c];
      #pragma unroll
      for (int r = 0; r < 4; ++r) {
        int m0 = mrow + r;
        arena[m0*68 + c] = xf[m0*64 + c] + bias + c0[r];
        if (m0+16 < SHORTN) arena[(m0+16)*68 + c] = xf[(m0+16)*64 + c] + bias + c1[r];
        if (m0+32 < SHORTN) arena[(m0+32)*68 + c] = xf[(m0+32)*64 + c] + bias + c2[r];
        if (m0+48 < SHORTN) arena[(m0+48)*68 + c] = xf[(m0+48)*64 + c] + bias + c3[r];
      }
      for (int idx = tid; idx < 14*F1ROW; idx += 256) f1bf[50*F1ROW + idx] = 0;
    }
    __syncthreads();

    // ======== LN1 ========
    {
      const float g = ln1_g[l*64 + lane], bb = ln1_b[l*64 + lane];
      for (int s = wid; s < SHORTN; s += 4) {
        float y = arena[s*68 + lane];
        float mean = wave_sum(y) * (1.f/64.f);
        float dv = y - mean;
        float var = wave_sum(dv*dv) * (1.f/64.f);
        float r = dv / sqrtf(var + 1e-5f) * g + bb;
        xf[s*64 + lane] = r;
        xbf[s*BROW + lane] = (short)f2bf(r);
      }
    }
    __syncthreads();

    // ======== ff1 ========
    {
      const short* ap = xbf + n16*BROW + kg8;
      bf16x8 A00 = *(const bf16x8*)(ap);            bf16x8 A01 = *(const bf16x8*)(ap + 32);
      bf16x8 A10 = *(const bf16x8*)(ap + 16*BROW);  bf16x8 A11 = *(const bf16x8*)(ap + 16*BROW + 32);
      bf16x8 A20 = *(const bf16x8*)(ap + 32*BROW);  bf16x8 A21 = *(const bf16x8*)(ap + 32*BROW + 32);
      bf16x8 A30 = *(const bf16x8*)(ap + 48*BROW);  bf16x8 A31 = *(const bf16x8*)(ap + 48*BROW + 32);
      #pragma unroll
      for (int t = 0; t < 2; ++t) {
        const int nt = wid*2 + t;
        const short* bp = wF + (size_t)(64 + l*16 + nt*2)*512 + lane*8;
        bf16x8 B0 = *(const bf16x8*)(bp);
        bf16x8 B1 = *(const bf16x8*)(bp + 512);
        f32x4 c0={0,0,0,0}, c1={0,0,0,0}, c2={0,0,0,0}, c3={0,0,0,0};
        c0 = __builtin_amdgcn_mfma_f32_16x16x32_bf16(A00, B0, c0, 0,0,0);
        c0 = __builtin_amdgcn_mfma_f32_16x16x32_bf16(A01, B1, c0, 0,0,0);
        c1 = __builtin_amdgcn_mfma_f32_16x16x32_bf16(A10, B0, c1, 0,0,0);
        c1 = __builtin_amdgcn_mfma_f32_16x16x32_bf16(A11, B1, c1, 0,0,0);
        c2 = __builtin_amdgcn_mfma_f32_16x16x32_bf16(A20, B0, c2, 0,0,0);
        c2 = __builtin_amdgcn_mfma_f32_16x16x32_bf16(A21, B1, c2, 0,0,0);
        c3 = __builtin_amdgcn_mfma_f32_16x16x32_bf16(A30, B0, c3, 0,0,0);
        c3 = __builtin_amdgcn_mfma_f32_16x16x32_bf16(A31, B1, c3, 0,0,0);
        const int c = nt*16 + n16;
        const float bias = ff1_b[l*128 + c];
        #pragma unroll
        for (int r = 0; r < 4; ++r) {
          int m0 = mrow + r;
          f1bf[m0*F1ROW + c] = (short)f2bf(fmaxf(c0[r] + bias, 0.f));
          if (m0+16 < SHORTN) f1bf[(m0+16)*F1ROW + c] = (short)f2bf(fmaxf(c1[r] + bias, 0.f));
          if (m0+32 < SHORTN) f1bf[(m0+32)*F1ROW + c] = (short)f2bf(fmaxf(c2[r] + bias, 0.f));
          if (m0+48 < SHORTN) f1bf[(m0+48)*F1ROW + c] = (short)f2bf(fmaxf(c3[r] + bias, 0.f));
        }
      }
    }
    __syncthreads();

    // ======== ff2 ========
    {
      const int nt = wid;
      f32x4 c0={0,0,0,0}, c1={0,0,0,0}, c2={0,0,0,0}, c3={0,0,0,0};
      #pragma unroll
      for (int kc = 0; kc < 4; ++kc) {
        const short* ap = f1bf + n16*F1ROW + kc*32 + kg8;
        bf16x8 A0 = *(const bf16x8*)(ap);
        bf16x8 A1 = *(const bf16x8*)(ap + 16*F1ROW);
        bf16x8 A2 = *(const bf16x8*)(ap + 32*F1ROW);
        bf16x8 A3 = *(const bf16x8*)(ap + 48*F1ROW);
        const short* bp = wF + (size_t)(96 + l*16 + nt*4 + kc)*512 + lane*8;
        bf16x8 B = *(const bf16x8*)(bp);
        c0 = __builtin_amdgcn_mfma_f32_16x16x32_bf16(A0, B, c0, 0,0,0);
        c1 = __builtin_amdgcn_mfma_f32_16x16x32_bf16(A1, B, c1, 0,0,0);
        c2 = __builtin_amdgcn_mfma_f32_16x16x32_bf16(A2, B, c2, 0,0,0);
        c3 = __builtin_amdgcn_mfma_f32_16x16x32_bf16(A3, B, c3, 0,0,0);
      }
      __syncthreads();
      const int c = nt*16 + n16;
      const float bias = ff2_b[l*64 + c];
      #pragma unroll
      for (int r = 0; r < 4; ++r) {
        int m0 = mrow + r;
        arena[m0*68 + c] = xf[m0*64 + c] + bias + c0[r];
        if (m0+16 < SHORTN) arena[(m0+16)*68 + c] = xf[(m0+16)*64 + c] + bias + c1[r];
        if (m0+32 < SHORTN) arena[(m0+32)*68 + c] = xf[(m0+32)*64 + c] + bias + c2[r];
        if (m0+48 < SHORTN) arena[(m0+48)*68 + c] = xf[(m0+48)*64 + c] + bias + c3[r];
      }
    }
    __syncthreads();

    // ======== LN2 ========
    {
      const float g = ln2_g[l*64 + lane], bb = ln2_b[l*64 + lane];
      for (int s = wid; s < SHORTN; s += 4) {
        float y = arena[s*68 + lane];
        float mean = wave_sum(y) * (1.f/64.f);
        float dv = y - mean;
        float var = wave_sum(dv*dv) * (1.f/64.f);
        float r = dv / sqrtf(var + 1e-5f) * g + bb;
        xf[s*64 + lane] = r;
        xbf[s*BROW + lane] = (short)f2bf(r);
      }
    }
    __syncthreads();
  }

  float acc = 0.f;
  for (int s = wid; s < SHORTN; s += 4) acc += xf[s*64 + lane];
  qf[wid*64 + lane] = acc;
  __syncthreads();
  if (wid == 0)
    bst_out[b*64 + lane] = (qf[lane] + qf[64+lane] + qf[128+lane] + qf[192+lane]) * (1.f/50.f);
}

// ===========================================================================
// Merged main kernel: grid 1536. blk%3<2 -> hard_scores block, ==2 -> bst.
// Interleaved so each CU co-schedules heterogeneous work.
// ===========================================================================
__global__ __launch_bounds__(256) void main_kernel(
    const int* __restrict__ target_item_id,
    const int* __restrict__ long_hist_ids,
    const int* __restrict__ short_hist_ids,
    const float* __restrict__ item_emb,
    const float* __restrict__ tproj_w, const float* __restrict__ tproj_b,
    const float* __restrict__ attn_w1, const float* __restrict__ attn_b1,
    const float* __restrict__ attn_w2, const float* __restrict__ attn_b2,
    const float* __restrict__ hash_emb,
    const short* __restrict__ wF,
    const float* __restrict__ qkv_b, const float* __restrict__ out_b,
    const float* __restrict__ ln1_g, const float* __restrict__ ln1_b,
    const float* __restrict__ ff1_b, const float* __restrict__ ff2_b,
    const float* __restrict__ ln2_g, const float* __restrict__ ln2_b,
    float* __restrict__ scores_ws, float* __restrict__ partA,
    float* __restrict__ partH, float* __restrict__ bst_out)
{
  extern __shared__ __align__(16) char smraw[];
  const int blk = blockIdx.x;
  const int r3 = blk % 3;
  if (r3 < 2) {
    hard_scores_path((blk/3)*2 + r3, (HardSM*)smraw,
        target_item_id, long_hist_ids, item_emb, tproj_w, tproj_b,
        attn_w1, attn_b1, attn_w2, attn_b2, hash_emb,
        scores_ws, partA, partH);
  } else {
    bst_path(blk/3, (BstSM*)smraw,
        short_hist_ids, item_emb, wF, qkv_b, out_b,
        ln1_g, ln1_b, ff1_b, ff2_b, ln2_g, ln2_b, bst_out);
  }
}

// ===========================================================================
// K2: softmax(1000) + bitonic top-50 + re-softmax + hard/soft repr. grid=NB.
// (unchanged from R9)
// ===========================================================================
__global__ __launch_bounds__(256) void hard_finish_kernel(
    const int* __restrict__ long_hist_ids,
    const float* __restrict__ item_emb,
    const float* __restrict__ sdim_w, const float* __restrict__ sdim_b,
    const float* __restrict__ scores_ws,
    const float* __restrict__ partA, const float* __restrict__ partH,
    float* __restrict__ hard_out, float* __restrict__ soft_out)
{
  __shared__ __align__(16) float scores[LONGN];
  __shared__ int   idsL[LONGN];
  __shared__ __align__(16) unsigned long long kv[1024];
  __shared__ __align__(16) float redE[4*64];
  __shared__ __align__(16) float vecbuf[64];
  __shared__ float redV[4];
  __shared__ float selV[TOPKN];
  __shared__ int   selI[TOPKN];

  const int b = blockIdx.x;
  const int tid = threadIdx.x;
  const int wid = tid >> 6, lane = tid & 63;

  for (int l = tid; l < LONGN; l += 256) {
    scores[l] = scores_ws[b*LONGN + l];
    idsL[l] = long_hist_ids[b*LONGN + l];
  }
  __syncthreads();

  if (tid < 64)
    vecbuf[tid] = (partA[(2*b)*64 + tid] + partA[(2*b+1)*64 + tid]
                 + partH[(2*b)*64 + tid] + partH[(2*b+1)*64 + tid]) * (1.f/1000.f);
  __syncthreads();
  if (tid < 64)
    soft_out[b*64 + tid] = sdim_b[tid] + dotN<64>(sdim_w + tid*64, vecbuf);

  float mx = -INFINITY;
  for (int l = tid; l < LONGN; l += 256) mx = fmaxf(mx, scores[l]);
  mx = wave_max(mx);
  if (lane == 0) redV[wid] = mx;
  __syncthreads();
  mx = fmaxf(fmaxf(redV[0], redV[1]), fmaxf(redV[2], redV[3]));
  __syncthreads();
  float sm = 0.f;
  for (int l = tid; l < LONGN; l += 256) {
    float a = expf(scores[l] - mx);
    scores[l] = a;
    sm += a;
  }
  sm = wave_sum(sm);
  if (lane == 0) redV[wid] = sm;
  __syncthreads();
  {
    const float inv = 1.f / (redV[0] + redV[1] + redV[2] + redV[3]);
    for (int l = tid; l < LONGN; l += 256) scores[l] *= inv;
  }
  __syncthreads();

  for (int l = tid; l < 1024; l += 256) {
    if (l < LONGN) {
      unsigned vb = __float_as_uint(scores[l]);
      kv[l] = ((unsigned long long)(~vb) << 32) | (unsigned)l;
    } else {
      kv[l] = 0xFFFFFFFFFFFFFFFFull;
    }
  }
  __syncthreads();

  for (int k = 2; k <= 1024; k <<= 1) {
    for (int j = k >> 1; j > 0; j >>= 1) {
      #pragma unroll 2
      for (int p = tid; p < 512; p += 256) {
        const int i = ((p & ~(j-1)) << 1) | (p & (j-1));
        const int m = i + j;
        const bool up = ((i & k) == 0);
        unsigned long long a = kv[i], c = kv[m];
        if ((a > c) == up) { kv[i] = c; kv[m] = a; }
      }
      __syncthreads();
    }
  }

  if (tid < TOPKN) {
    unsigned long long key = kv[tid];
    selI[tid] = (int)(unsigned)(key & 0xFFFFFFFFu);
    selV[tid] = __uint_as_float(~(unsigned)(key >> 32));
  }
  __syncthreads();

  if (wid == 0) {
    float v = (lane < TOPKN) ? selV[lane] : -INFINITY;
    float m2 = wave_max(v);
    float e = (lane < TOPKN) ? expf(v - m2) : 0.f;
    float s2 = wave_sum(e);
    if (lane < TOPKN) selV[lane] = e / s2;
  }
  __syncthreads();

  float accR = 0.f;
  for (int r = wid; r < TOPKN; r += 4)
    accR += selV[r] * item_emb[idsL[selI[r]]*64 + lane];
  redE[wid*64 + lane] = accR;
  __syncthreads();
  if (wid == 0)
    hard_out[b*64 + lane] = redE[lane] + redE[64+lane] + redE[128+lane] + redE[192+lane];
}

// ===========================================================================
// BST weight prep (unchanged from R9).
// ===========================================================================
__global__ __launch_bounds__(256) void bst_prep_kernel(
    const float* __restrict__ qkv_w, const float* __restrict__ out_w,
    const float* __restrict__ ff1_w, const float* __restrict__ ff2_w,
    short* __restrict__ wF)
{
  const int t = blockIdx.x*256 + threadIdx.x;   // 8192 threads
  if (t >= 8192) return;
  const int fid = t >> 6, lane = t & 63;
  const int n16 = lane & 15, k8 = (lane >> 4) * 8;
  const float* src;
  if (fid < 48)      { int f=fid,    l=f/24, r=f%24, nt=r>>1, kc=r&1;
    src = qkv_w + l*12288 + (nt*16+n16)*64 + kc*32 + k8; }
  else if (fid < 64) { int f=fid-48, l=f>>3, r=f&7,  nt=r>>1, kc=r&1;
    src = out_w + l*4096 + (nt*16+n16)*64 + kc*32 + k8; }
  else if (fid < 96) { int f=fid-64, l=f>>4, r=f&15, nt=r>>1, kc=r&1;
    src = ff1_w + l*8192 + (nt*16+n16)*64 + kc*32 + k8; }
  else               { int f=fid-96, l=f>>4, r=f&15, nt=r>>2, kc=r&3;
    src = ff2_w + l*8192 + (nt*16+n16)*128 + kc*32 + k8; }
  short* dst = wF + fid*512 + lane*8;
  #pragma unroll
  for (int j = 0; j < 8; ++j) dst[j] = (short)f2bf(src[j]);
}

// ===========================================================================
// Fusion MLP. (unchanged)
// ===========================================================================
__global__ __launch_bounds__(256) void fusion_kernel(
    const float* __restrict__ user, const float* __restrict__ hard,
    const float* __restrict__ soft, const float* __restrict__ bst,
    const float* __restrict__ w1, const float* __restrict__ b1,
    const float* __restrict__ w2, const float* __restrict__ b2,
    const float* __restrict__ w3, const float* __restrict__ b3,
    float* __restrict__ out)
{
  __shared__ __align__(16) float comb[256];
  __shared__ __align__(16) float h1[256];
  __shared__ __align__(16) float h2[128];
  const int b = blockIdx.x, tid = threadIdx.x;
  if (tid < 64)       comb[tid] = user[b*64 + tid];
  else if (tid < 128) comb[tid] = hard[b*64 + tid - 64];
  else if (tid < 192) comb[tid] = soft[b*64 + tid - 128];
  else                comb[tid] = bst[b*64 + tid - 192];
  __syncthreads();
  h1[tid] = fmaxf(b1[tid] + dotN<256>(w1 + tid*256, comb), 0.f);
  __syncthreads();
  if (tid < 128) h2[tid] = fmaxf(b2[tid] + dotN<256>(w2 + tid*256, h1), 0.f);
  __syncthreads();
  if (tid < 64) {
    float p = w3[tid]*h2[tid] + w3[tid+64]*h2[tid+64];
    p = wave_sum(p);
    if (tid == 0) out[b] = p + b3[0];
  }
}

extern "C" void kernel_launch(void* const* d_in, const int* in_sizes, int n_in,
                              void* d_out, int out_size, void* d_ws, size_t ws_size,
                              hipStream_t stream) {
  const float* user_features  = (const float*)d_in[0];
  const int*   target_item_id = (const int*)  d_in[1];
  const int*   short_hist_ids = (const int*)  d_in[2];
  const int*   long_hist_ids  = (const int*)  d_in[3];
  const float* item_emb       = (const float*)d_in[4];
  const float* tproj_w  = (const float*)d_in[5];
  const float* tproj_b  = (const float*)d_in[6];
  const float* attn_w1  = (const float*)d_in[7];
  const float* attn_b1  = (const float*)d_in[8];
  const float* attn_w2  = (const float*)d_in[9];
  const float* attn_b2  = (const float*)d_in[10];
  const float* hash_emb = (const float*)d_in[11];
  const float* sdim_w   = (const float*)d_in[12];
  const float* sdim_b   = (const float*)d_in[13];
  const float* tf_qkv_w = (const float*)d_in[14];
  const float* tf_qkv_b = (const float*)d_in[15];
  const float* tf_out_w = (const float*)d_in[16];
  const float* tf_out_b = (const float*)d_in[17];
  const float* tf_ln1_g = (const float*)d_in[18];
  const float* tf_ln1_b = (const float*)d_in[19];
  const float* tf_ff1_w = (const float*)d_in[20];
  const float* tf_ff1_b = (const float*)d_in[21];
  const float* tf_ff2_w = (const float*)d_in[22];
  const float* tf_ff2_b = (const float*)d_in[23];
  const float* tf_ln2_g = (const float*)d_in[24];
  const float* tf_ln2_b = (const float*)d_in[25];
  const float* fus_w1   = (const float*)d_in[26];
  const float* fus_b1   = (const float*)d_in[27];
  const float* fus_w2   = (const float*)d_in[28];
  const float* fus_b2   = (const float*)d_in[29];
  const float* fus_w3   = (const float*)d_in[30];
  const float* fus_b3   = (const float*)d_in[31];

  float* ws = (float*)d_ws;
  float* hard = ws;                    // NB*64
  float* soft = hard + NB*64;          // NB*64
  float* bst  = soft + NB*64;          // NB*64
  float* scores_ws = bst + NB*64;      // NB*1000
  float* partA = scores_ws + NB*LONGN; // NB*2*64
  float* partH = partA + NB*2*64;      // NB*2*64
  short* wF    = (short*)(partH + NB*2*64); // 65536 shorts (128 KB)

  constexpr size_t lds_bytes =
      sizeof(BstSM) > sizeof(HardSM) ? sizeof(BstSM) : sizeof(HardSM);

  bst_prep_kernel<<<32, 256, 0, stream>>>(tf_qkv_w, tf_out_w, tf_ff1_w, tf_ff2_w, wF);
  main_kernel<<<3*NB, 256, lds_bytes, stream>>>(
      target_item_id, long_hist_ids, short_hist_ids, item_emb,
      tproj_w, tproj_b, attn_w1, attn_b1, attn_w2, attn_b2, hash_emb,
      wF, tf_qkv_b, tf_out_b, tf_ln1_g, tf_ln1_b, tf_ff1_b, tf_ff2_b,
      tf_ln2_g, tf_ln2_b,
      scores_ws, partA, partH, bst);
  hard_finish_kernel<<<NB, 256, 0, stream>>>(long_hist_ids, item_emb,
      sdim_w, sdim_b, scores_ws, partA, partH, hard, soft);
  fusion_kernel<<<NB, 256, 0, stream>>>(user_features, hard, soft, bst,
      fus_w1, fus_b1, fus_w2, fus_b2, fus_w3, fus_b3, (float*)d_out);
}

// Round 11
// 201.666 us; speedup vs baseline: 1.1072x; 1.1072x over previous
//
#include <hip/hip_runtime.h>
#include <math.h>

#define NB 512
#define LONGN 1000
#define SHORTN 50
#define TOPKN 50
#define HALFN 500
#define NG 8          // item-groups per hard block
#define EROW 72       // hard-path bf16 LDS row stride (shorts)
#define BROW 72       // bst bf16 row stride (shorts) for xbf/obf
#define F1ROW 136     // bst bf16 row stride for ff1 output (128+8)
#define KVROW 136     // bst bf16 kv row stride (shorts)

typedef __attribute__((ext_vector_type(8))) short bf16x8;
typedef __attribute__((ext_vector_type(4))) float f32x4;

__device__ __forceinline__ float dot4(float4 a, float4 b) {
  return a.x*b.x + a.y*b.y + a.z*b.z + a.w*b.w;
}

template<int N>
__device__ __forceinline__ float dotN(const float* w, const float* x) {
  const float4* w4 = (const float4*)w;
  const float4* x4 = (const float4*)x;
  float a0 = 0.f, a1 = 0.f, a2 = 0.f, a3 = 0.f;
  #pragma unroll
  for (int k = 0; k < N/4; k += 4) {
    a0 += dot4(w4[k],   x4[k]);
    a1 += dot4(w4[k+1], x4[k+1]);
    a2 += dot4(w4[k+2], x4[k+2]);
    a3 += dot4(w4[k+3], x4[k+3]);
  }
  return (a0 + a1) + (a2 + a3);
}

__device__ __forceinline__ float wave_sum(float v) {
  #pragma unroll
  for (int off = 32; off > 0; off >>= 1) v += __shfl_xor(v, off);
  return v;
}
__device__ __forceinline__ float wave_max(float v) {
  #pragma unroll
  for (int off = 32; off > 0; off >>= 1) v = fmaxf(v, __shfl_xor(v, off));
  return v;
}

__device__ __forceinline__ unsigned short f2bf(float x) {  // RNE fp32->bf16
  unsigned u = __float_as_uint(x);
  return (unsigned short)((u + 0x7fffu + ((u >> 16) & 1u)) >> 16);
}
__device__ __forceinline__ float bf2f(short s) {           // bf16->fp32
  return __uint_as_float(((unsigned)(unsigned short)s) << 16);
}

// ===========================================================================
// emb prep: f32 item table -> bf16 copy in ws (one-time, ~38MB traffic).
// ===========================================================================
__global__ __launch_bounds__(256) void emb_prep_kernel(
    const float* __restrict__ emb, short* __restrict__ embT, int n8)
{
  const int t = blockIdx.x*256 + threadIdx.x;
  if (t >= n8) return;
  const float4* s = (const float4*)(emb + (size_t)t*8);
  float4 a = s[0], b = s[1];
  bf16x8 w;
  w[0]=(short)f2bf(a.x); w[1]=(short)f2bf(a.y); w[2]=(short)f2bf(a.z); w[3]=(short)f2bf(a.w);
  w[4]=(short)f2bf(b.x); w[5]=(short)f2bf(b.y); w[6]=(short)f2bf(b.z); w[7]=(short)f2bf(b.w);
  *(bf16x8*)(embT + (size_t)t*8) = w;
}

// ===========================================================================
// K1 (MFMA): hard-search scores. bf16-table gather path (halved bytes) with
// f32 fallback if ws too small. grid = 2*NB.
// ===========================================================================
__global__ __launch_bounds__(256, 3) void hard_scores_kernel(
    const int* __restrict__ target_item_id,
    const int* __restrict__ long_hist_ids,
    const float* __restrict__ item_emb,
    const short* __restrict__ embT, const int use_bf16,
    const float* __restrict__ tproj_w, const float* __restrict__ tproj_b,
    const float* __restrict__ attn_w1, const float* __restrict__ attn_b1,
    const float* __restrict__ attn_w2, const float* __restrict__ attn_b2,
    const float* __restrict__ hash_emb,
    float* __restrict__ scores_ws, float* __restrict__ partA,
    float* __restrict__ partH)
{
  __shared__ __align__(16) short Abf[64*EROW];
  __shared__ __align__(16) short Ebuf[2][64*EROW];
  __shared__ __align__(16) float tv[64];
  __shared__ __align__(16) float te[64];
  __shared__ __align__(16) float2 cw[64];
  __shared__ int idsL[HALFN];
  __shared__ __align__(16) float redE[4*64];

  const int bid = blockIdx.x;
  const int b = bid >> 1, half = bid & 1;
  const int base = half * HALFN;
  const int tid = threadIdx.x;
  const int wid = tid >> 6, lane = tid & 63;

  if (tid < 64) tv[tid] = item_emb[target_item_id[b]*64 + tid];
  for (int l = tid; l < HALFN; l += 256) idsL[l] = long_hist_ids[b*LONGN + base + l];
  __syncthreads();
  if (tid < 64) te[tid] = tproj_b[tid] + dotN<64>(tproj_w + tid*64, tv);
  __syncthreads();
  if (tid < 64) {
    float c = attn_b1[tid] + dotN<64>(attn_w1 + tid*192, te);
    cw[tid] = make_float2(c, attn_w2[tid]);
  }
  for (int idx = tid; idx < 4096; idx += 256) {
    int i = idx >> 6, j = idx & 63;
    Abf[i*EROW + j] = (short)f2bf(attn_w1[i*192 + 64 + j] + attn_w1[i*192 + 128 + j]*te[j]);
  }
  __syncthreads();

  bf16x8 a00,a01,a10,a11,a20,a21,a30,a31;
  {
    const short* ap = Abf + (lane & 15)*EROW + ((lane >> 4) << 3);
    a00 = *(const bf16x8*)(ap +  0*EROW);  a01 = *(const bf16x8*)(ap +  0*EROW + 32);
    a10 = *(const bf16x8*)(ap + 16*EROW);  a11 = *(const bf16x8*)(ap + 16*EROW + 32);
    a20 = *(const bf16x8*)(ap + 32*EROW);  a21 = *(const bf16x8*)(ap + 32*EROW + 32);
    a30 = *(const bf16x8*)(ap + 48*EROW);  a31 = *(const bf16x8*)(ap + 48*EROW + 32);
  }

  const float b2s = attn_b2[0];
  const int it_g = tid >> 2;
  const int dimg = (tid & 3) * 16;

  float4 sE0 = {0,0,0,0}, sE1 = {0,0,0,0}, sE2 = {0,0,0,0}, sE3 = {0,0,0,0};

  // ---- prologue: stage group 0 ----
  {
    bf16x8 w0, w1;
    if (use_bf16) {
      const bf16x8* ep = (const bf16x8*)(embT + (size_t)idsL[it_g]*64 + dimg);
      w0 = ep[0]; w1 = ep[1];
      sE0.x+=bf2f(w0[0]); sE0.y+=bf2f(w0[1]); sE0.z+=bf2f(w0[2]); sE0.w+=bf2f(w0[3]);
      sE1.x+=bf2f(w0[4]); sE1.y+=bf2f(w0[5]); sE1.z+=bf2f(w0[6]); sE1.w+=bf2f(w0[7]);
      sE2.x+=bf2f(w1[0]); sE2.y+=bf2f(w1[1]); sE2.z+=bf2f(w1[2]); sE2.w+=bf2f(w1[3]);
      sE3.x+=bf2f(w1[4]); sE3.y+=bf2f(w1[5]); sE3.z+=bf2f(w1[6]); sE3.w+=bf2f(w1[7]);
    } else {
      const float4* ep = (const float4*)(item_emb + (size_t)idsL[it_g]*64 + dimg);
      float4 r0 = ep[0], r1 = ep[1], r2 = ep[2], r3 = ep[3];
      sE0.x+=r0.x; sE0.y+=r0.y; sE0.z+=r0.z; sE0.w+=r0.w;
      sE1.x+=r1.x; sE1.y+=r1.y; sE1.z+=r1.z; sE1.w+=r1.w;
      sE2.x+=r2.x; sE2.y+=r2.y; sE2.z+=r2.z; sE2.w+=r2.w;
      sE3.x+=r3.x; sE3.y+=r3.y; sE3.z+=r3.z; sE3.w+=r3.w;
      w0[0]=(short)f2bf(r0.x); w0[1]=(short)f2bf(r0.y); w0[2]=(short)f2bf(r0.z); w0[3]=(short)f2bf(r0.w);
      w0[4]=(short)f2bf(r1.x); w0[5]=(short)f2bf(r1.y); w0[6]=(short)f2bf(r1.z); w0[7]=(short)f2bf(r1.w);
      w1[0]=(short)f2bf(r2.x); w1[1]=(short)f2bf(r2.y); w1[2]=(short)f2bf(r2.z); w1[3]=(short)f2bf(r2.w);
      w1[4]=(short)f2bf(r3.x); w1[5]=(short)f2bf(r3.y); w1[6]=(short)f2bf(r3.z); w1[7]=(short)f2bf(r3.w);
    }
    short* dst = &Ebuf[0][it_g*EROW + dimg];
    *(bf16x8*)dst = w0;  *(bf16x8*)(dst + 8) = w1;
  }
  __syncthreads();

  // ---- main loop: stage g+1 (async-split) while MFMA on g ----
  int buf = 0;
  for (int g = 0; g < NG; ++g) {
    bf16x8 w0 = {0,0,0,0,0,0,0,0}, w1 = {0,0,0,0,0,0,0,0};
    float4 r0={0,0,0,0}, r1={0,0,0,0}, r2={0,0,0,0}, r3={0,0,0,0};
    const bool more = (g + 1 < NG);
    if (more) {
      const int gi = (g+1)*64 + it_g;
      if (gi < HALFN) {
        if (use_bf16) {
          const bf16x8* ep = (const bf16x8*)(embT + (size_t)idsL[gi]*64 + dimg);
          w0 = ep[0]; w1 = ep[1];
        } else {
          const float4* ep = (const float4*)(item_emb + (size_t)idsL[gi]*64 + dimg);
          r0 = ep[0]; r1 = ep[1]; r2 = ep[2]; r3 = ep[3];
        }
      }
    }

    f32x4 acc0={0,0,0,0}, acc1={0,0,0,0}, acc2={0,0,0,0}, acc3={0,0,0,0};
    {
      const short* ep = &Ebuf[buf][(wid*16 + (lane & 15))*EROW + ((lane >> 4) << 3)];
      bf16x8 b0 = *(const bf16x8*)(ep);
      bf16x8 b1 = *(const bf16x8*)(ep + 32);
      acc0 = __builtin_amdgcn_mfma_f32_16x16x32_bf16(a00, b0, acc0, 0, 0, 0);
      acc0 = __builtin_amdgcn_mfma_f32_16x16x32_bf16(a01, b1, acc0, 0, 0, 0);
      acc1 = __builtin_amdgcn_mfma_f32_16x16x32_bf16(a10, b0, acc1, 0, 0, 0);
      acc1 = __builtin_amdgcn_mfma_f32_16x16x32_bf16(a11, b1, acc1, 0, 0, 0);
      acc2 = __builtin_amdgcn_mfma_f32_16x16x32_bf16(a20, b0, acc2, 0, 0, 0);
      acc2 = __builtin_amdgcn_mfma_f32_16x16x32_bf16(a21, b1, acc2, 0, 0, 0);
      acc3 = __builtin_amdgcn_mfma_f32_16x16x32_bf16(a30, b0, acc3, 0, 0, 0);
      acc3 = __builtin_amdgcn_mfma_f32_16x16x32_bf16(a31, b1, acc3, 0, 0, 0);
    }
    float p = 0.f;
    {
      const int rbase = (lane >> 4) << 2;
      #pragma unroll
      for (int r = 0; r < 4; ++r) {
        float2 c0 = cw[ 0 + rbase + r];
        float2 c1 = cw[16 + rbase + r];
        float2 c2 = cw[32 + rbase + r];
        float2 c3 = cw[48 + rbase + r];
        p += c0.y * fmaxf(acc0[r] + c0.x, 0.f);
        p += c1.y * fmaxf(acc1[r] + c1.x, 0.f);
        p += c2.y * fmaxf(acc2[r] + c2.x, 0.f);
        p += c3.y * fmaxf(acc3[r] + c3.x, 0.f);
      }
    }
    p += __shfl_xor(p, 16);
    p += __shfl_xor(p, 32);
    if (lane < 16) {
      const int gi = g*64 + wid*16 + lane;
      if (gi < HALFN) scores_ws[b*LONGN + base + gi] = b2s + p;
    }

    if (more) {
      if (use_bf16) {
        sE0.x+=bf2f(w0[0]); sE0.y+=bf2f(w0[1]); sE0.z+=bf2f(w0[2]); sE0.w+=bf2f(w0[3]);
        sE1.x+=bf2f(w0[4]); sE1.y+=bf2f(w0[5]); sE1.z+=bf2f(w0[6]); sE1.w+=bf2f(w0[7]);
        sE2.x+=bf2f(w1[0]); sE2.y+=bf2f(w1[1]); sE2.z+=bf2f(w1[2]); sE2.w+=bf2f(w1[3]);
        sE3.x+=bf2f(w1[4]); sE3.y+=bf2f(w1[5]); sE3.z+=bf2f(w1[6]); sE3.w+=bf2f(w1[7]);
      } else {
        sE0.x+=r0.x; sE0.y+=r0.y; sE0.z+=r0.z; sE0.w+=r0.w;
        sE1.x+=r1.x; sE1.y+=r1.y; sE1.z+=r1.z; sE1.w+=r1.w;
        sE2.x+=r2.x; sE2.y+=r2.y; sE2.z+=r2.z; sE2.w+=r2.w;
        sE3.x+=r3.x; sE3.y+=r3.y; sE3.z+=r3.z; sE3.w+=r3.w;
        w0[0]=(short)f2bf(r0.x); w0[1]=(short)f2bf(r0.y); w0[2]=(short)f2bf(r0.z); w0[3]=(short)f2bf(r0.w);
        w0[4]=(short)f2bf(r1.x); w0[5]=(short)f2bf(r1.y); w0[6]=(short)f2bf(r1.z); w0[7]=(short)f2bf(r1.w);
        w1[0]=(short)f2bf(r2.x); w1[1]=(short)f2bf(r2.y); w1[2]=(short)f2bf(r2.z); w1[3]=(short)f2bf(r2.w);
        w1[4]=(short)f2bf(r3.x); w1[5]=(short)f2bf(r3.y); w1[6]=(short)f2bf(r3.z); w1[7]=(short)f2bf(r3.w);
      }
      short* dst = &Ebuf[buf ^ 1][it_g*EROW + dimg];
      *(bf16x8*)dst = w0;  *(bf16x8*)(dst + 8) = w1;
    }
    __syncthreads();
    buf ^= 1;
  }

  {
    float* red = (float*)&Ebuf[0][0];
    const int b17 = tid * 17;
    red[b17+ 0]=sE0.x; red[b17+ 1]=sE0.y; red[b17+ 2]=sE0.z; red[b17+ 3]=sE0.w;
    red[b17+ 4]=sE1.x; red[b17+ 5]=sE1.y; red[b17+ 6]=sE1.z; red[b17+ 7]=sE1.w;
    red[b17+ 8]=sE2.x; red[b17+ 9]=sE2.y; red[b17+10]=sE2.z; red[b17+11]=sE2.w;
    red[b17+12]=sE3.x; red[b17+13]=sE3.y; red[b17+14]=sE3.z; red[b17+15]=sE3.w;
    __syncthreads();
    if (tid < 64) {
      const int dg = tid >> 4, dw = tid & 15;
      float s = 0.f;
      for (int j = 0; j < 64; ++j) s += red[(j*4 + dg)*17 + dw];
      partA[bid*64 + tid] = s;
    }
  }

  {
    const int hl = lane >> 4, dd = lane & 15;
    const float* hb = hash_emb + hl*1024*16 + dd;
    float accH = 0.f;
    for (int l = wid; l < HALFN; l += 4)
      accH += hb[(idsL[l] & 1023)*16];
    redE[wid*64 + lane] = accH;
  }
  __syncthreads();
  if (wid == 0)
    partH[bid*64 + lane] = redE[lane] + redE[64+lane] + redE[128+lane] + redE[192+lane];
}

// ===========================================================================
// K2: softmax(1000) + bitonic top-50 + re-softmax + hard/soft repr. grid=NB.
// (unchanged from R9)
// ===========================================================================
__global__ __launch_bounds__(256) void hard_finish_kernel(
    const int* __restrict__ long_hist_ids,
    const float* __restrict__ item_emb,
    const float* __restrict__ sdim_w, const float* __restrict__ sdim_b,
    const float* __restrict__ scores_ws,
    const float* __restrict__ partA, const float* __restrict__ partH,
    float* __restrict__ hard_out, float* __restrict__ soft_out)
{
  __shared__ __align__(16) float scores[LONGN];
  __shared__ int   idsL[LONGN];
  __shared__ __align__(16) unsigned long long kv[1024];
  __shared__ __align__(16) float redE[4*64];
  __shared__ __align__(16) float vecbuf[64];
  __shared__ float redV[4];
  __shared__ float selV[TOPKN];
  __shared__ int   selI[TOPKN];

  const int b = blockIdx.x;
  const int tid = threadIdx.x;
  const int wid = tid >> 6, lane = tid & 63;

  for (int l = tid; l < LONGN; l += 256) {
    scores[l] = scores_ws[b*LONGN + l];
    idsL[l] = long_hist_ids[b*LONGN + l];
  }
  __syncthreads();

  if (tid < 64)
    vecbuf[tid] = (partA[(2*b)*64 + tid] + partA[(2*b+1)*64 + tid]
                 + partH[(2*b)*64 + tid] + partH[(2*b+1)*64 + tid]) * (1.f/1000.f);
  __syncthreads();
  if (tid < 64)
    soft_out[b*64 + tid] = sdim_b[tid] + dotN<64>(sdim_w + tid*64, vecbuf);

  float mx = -INFINITY;
  for (int l = tid; l < LONGN; l += 256) mx = fmaxf(mx, scores[l]);
  mx = wave_max(mx);
  if (lane == 0) redV[wid] = mx;
  __syncthreads();
  mx = fmaxf(fmaxf(redV[0], redV[1]), fmaxf(redV[2], redV[3]));
  __syncthreads();
  float sm = 0.f;
  for (int l = tid; l < LONGN; l += 256) {
    float a = expf(scores[l] - mx);
    scores[l] = a;
    sm += a;
  }
  sm = wave_sum(sm);
  if (lane == 0) redV[wid] = sm;
  __syncthreads();
  {
    const float inv = 1.f / (redV[0] + redV[1] + redV[2] + redV[3]);
    for (int l = tid; l < LONGN; l += 256) scores[l] *= inv;
  }
  __syncthreads();

  for (int l = tid; l < 1024; l += 256) {
    if (l < LONGN) {
      unsigned vb = __float_as_uint(scores[l]);
      kv[l] = ((unsigned long long)(~vb) << 32) | (unsigned)l;
    } else {
      kv[l] = 0xFFFFFFFFFFFFFFFFull;
    }
  }
  __syncthreads();

  for (int k = 2; k <= 1024; k <<= 1) {
    for (int j = k >> 1; j > 0; j >>= 1) {
      #pragma unroll 2
      for (int p = tid; p < 512; p += 256) {
        const int i = ((p & ~(j-1)) << 1) | (p & (j-1));
        const int m = i + j;
        const bool up = ((i & k) == 0);
        unsigned long long a = kv[i], c = kv[m];
        if ((a > c) == up) { kv[i] = c; kv[m] = a; }
      }
      __syncthreads();
    }
  }

  if (tid < TOPKN) {
    unsigned long long key = kv[tid];
    selI[tid] = (int)(unsigned)(key & 0xFFFFFFFFu);
    selV[tid] = __uint_as_float(~(unsigned)(key >> 32));
  }
  __syncthreads();

  if (wid == 0) {
    float v = (lane < TOPKN) ? selV[lane] : -INFINITY;
    float m2 = wave_max(v);
    float e = (lane < TOPKN) ? expf(v - m2) : 0.f;
    float s2 = wave_sum(e);
    if (lane < TOPKN) selV[lane] = e / s2;
  }
  __syncthreads();

  float accR = 0.f;
  for (int r = wid; r < TOPKN; r += 4)
    accR += selV[r] * item_emb[idsL[selI[r]]*64 + lane];
  redE[wid*64 + lane] = accR;
  __syncthreads();
  if (wid == 0)
    hard_out[b*64 + lane] = redE[lane] + redE[64+lane] + redE[128+lane] + redE[192+lane];
}

// ===========================================================================
// BST weight prep (unchanged from R9).
// ===========================================================================
__global__ __launch_bounds__(256) void bst_prep_kernel(
    const float* __restrict__ qkv_w, const float* __restrict__ out_w,
    const float* __restrict__ ff1_w, const float* __restrict__ ff2_w,
    short* __restrict__ wF)
{
  const int t = blockIdx.x*256 + threadIdx.x;   // 8192 threads
  if (t >= 8192) return;
  const int fid = t >> 6, lane = t & 63;
  const int n16 = lane & 15, k8 = (lane >> 4) * 8;
  const float* src;
  if (fid < 48)      { int f=fid,    l=f/24, r=f%24, nt=r>>1, kc=r&1;
    src = qkv_w + l*12288 + (nt*16+n16)*64 + kc*32 + k8; }
  else if (fid < 64) { int f=fid-48, l=f>>3, r=f&7,  nt=r>>1, kc=r&1;
    src = out_w + l*4096 + (nt*16+n16)*64 + kc*32 + k8; }
  else if (fid < 96) { int f=fid-64, l=f>>4, r=f&15, nt=r>>1, kc=r&1;
    src = ff1_w + l*8192 + (nt*16+n16)*64 + kc*32 + k8; }
  else               { int f=fid-96, l=f>>4, r=f&15, nt=r>>2, kc=r&3;
    src = ff2_w + l*8192 + (nt*16+n16)*128 + kc*32 + k8; }
  short* dst = wF + fid*512 + lane*8;
  #pragma unroll
  for (int j = 0; j < 8; ++j) dst[j] = (short)f2bf(src[j]);
}

// ===========================================================================
// BST transformer v7 (MFMA + bf16 k/v in LDS). Residual/LN/q stay f32.
// LDS zone aliasing: (qf+kvbf) -> y -> f1bf -> y2. 58.4 KB total.
// ===========================================================================
__global__ __launch_bounds__(256) void bst_kernel(
    const int* __restrict__ short_ids, const float* __restrict__ item_emb,
    const short* __restrict__ wF,
    const float* __restrict__ qkv_b, const float* __restrict__ out_b,
    const float* __restrict__ ln1_g, const float* __restrict__ ln1_b,
    const float* __restrict__ ff1_b, const float* __restrict__ ff2_b,
    const float* __restrict__ ln2_g, const float* __restrict__ ln2_b,
    float* __restrict__ bst_out)
{
  __shared__ __align__(16) float xf[SHORTN*64];     // 12800 residual f32
  __shared__ __align__(16) short xbf[64*BROW];      //  9216 x bf16 (padded)
  __shared__ __align__(16) char  zone[27200];       // qf+kvbf -> y -> f1 -> y2
  __shared__ __align__(16) short obf[64*BROW];      //  9216 attn-out bf16

  float* qf   = (float*)zone;             // [50][68] f32
  short* kvbf = (short*)(zone + 13600);   // [50][136] bf16 (k: 0-63, v: 64-127)
  float* yln  = (float*)zone;             // [50][68] f32 (y / y2)
  short* f1bf = (short*)zone;             // [64][136] bf16

  const int b = blockIdx.x, tid = threadIdx.x;
  const int wid = tid >> 6, lane = tid & 63;
  const int n16 = lane & 15;
  const int kg8 = (lane >> 4) << 3;
  const int mrow = (lane >> 4) << 2;

  for (int idx = tid; idx < SHORTN*64; idx += 256) {
    int s = idx >> 6, j = idx & 63;
    float v = item_emb[short_ids[b*SHORTN + s]*64 + j];
    xf[idx] = v;
    xbf[s*BROW + j] = (short)f2bf(v);
  }
  for (int idx = tid; idx < 14*BROW; idx += 256) {
    xbf[50*BROW + idx] = 0;
    obf[50*BROW + idx] = 0;
  }
  __syncthreads();

  for (int l = 0; l < 2; ++l) {
    // ======== qkv: q -> qf (f32), k/v -> kvbf (bf16) ========
    {
      const short* ap = xbf + n16*BROW + kg8;
      bf16x8 A00 = *(const bf16x8*)(ap);            bf16x8 A01 = *(const bf16x8*)(ap + 32);
      bf16x8 A10 = *(const bf16x8*)(ap + 16*BROW);  bf16x8 A11 = *(const bf16x8*)(ap + 16*BROW + 32);
      bf16x8 A20 = *(const bf16x8*)(ap + 32*BROW);  bf16x8 A21 = *(const bf16x8*)(ap + 32*BROW + 32);
      bf16x8 A30 = *(const bf16x8*)(ap + 48*BROW);  bf16x8 A31 = *(const bf16x8*)(ap + 48*BROW + 32);
      #pragma unroll
      for (int t = 0; t < 3; ++t) {
        const int nt = wid*3 + t;
        const short* bp = wF + (size_t)(l*24 + nt*2)*512 + lane*8;
        bf16x8 B0 = *(const bf16x8*)(bp);
        bf16x8 B1 = *(const bf16x8*)(bp + 512);
        f32x4 c0={0,0,0,0}, c1={0,0,0,0}, c2={0,0,0,0}, c3={0,0,0,0};
        c0 = __builtin_amdgcn_mfma_f32_16x16x32_bf16(A00, B0, c0, 0,0,0);
        c0 = __builtin_amdgcn_mfma_f32_16x16x32_bf16(A01, B1, c0, 0,0,0);
        c1 = __builtin_amdgcn_mfma_f32_16x16x32_bf16(A10, B0, c1, 0,0,0);
        c1 = __builtin_amdgcn_mfma_f32_16x16x32_bf16(A11, B1, c1, 0,0,0);
        c2 = __builtin_amdgcn_mfma_f32_16x16x32_bf16(A20, B0, c2, 0,0,0);
        c2 = __builtin_amdgcn_mfma_f32_16x16x32_bf16(A21, B1, c2, 0,0,0);
        c3 = __builtin_amdgcn_mfma_f32_16x16x32_bf16(A30, B0, c3, 0,0,0);
        c3 = __builtin_amdgcn_mfma_f32_16x16x32_bf16(A31, B1, c3, 0,0,0);
        const int c = nt*16 + n16;
        const float bias = qkv_b[l*192 + c];
        #pragma unroll
        for (int r = 0; r < 4; ++r) {
          int m0 = mrow + r;
          float v0 = c0[r] + bias;
          float v1 = c1[r] + bias;
          float v2 = c2[r] + bias;
          float v3 = c3[r] + bias;
          if (c < 64) {
            qf[m0*68 + c] = v0;
            if (m0+16 < SHORTN) qf[(m0+16)*68 + c] = v1;
            if (m0+32 < SHORTN) qf[(m0+32)*68 + c] = v2;
            if (m0+48 < SHORTN) qf[(m0+48)*68 + c] = v3;
          } else {
            const int cc = c - 64;
            kvbf[m0*KVROW + cc] = (short)f2bf(v0);
            if (m0+16 < SHORTN) kvbf[(m0+16)*KVROW + cc] = (short)f2bf(v1);
            if (m0+32 < SHORTN) kvbf[(m0+32)*KVROW + cc] = (short)f2bf(v2);
            if (m0+48 < SHORTN) kvbf[(m0+48)*KVROW + cc] = (short)f2bf(v3);
          }
        }
      }
    }
    __syncthreads();

    // ======== attention: q f32, k/v bf16 (halved LDS reads), online softmax ===
    if (tid < 4*SHORTN) {
      const int h = tid / SHORTN, s = tid - h*SHORTN;
      const float4* qp = (const float4*)(qf + s*68 + h*16);
      const float4 qA = qp[0], qB2 = qp[1], qC = qp[2], qD = qp[3];
      float m = -INFINITY, ss = 0.f;
      float4 oa0 = {0,0,0,0}, oa1 = {0,0,0,0}, oa2 = {0,0,0,0}, oa3 = {0,0,0,0};
      for (int t2 = 0; t2 < SHORTN; ++t2) {
        const short* kp = kvbf + t2*KVROW + h*16;
        bf16x8 k0 = *(const bf16x8*)kp;
        bf16x8 k1 = *(const bf16x8*)(kp + 8);
        float d =
            qA.x*bf2f(k0[0]) + qA.y*bf2f(k0[1]) + qA.z*bf2f(k0[2]) + qA.w*bf2f(k0[3])
          + qB2.x*bf2f(k0[4]) + qB2.y*bf2f(k0[5]) + qB2.z*bf2f(k0[6]) + qB2.w*bf2f(k0[7])
          + qC.x*bf2f(k1[0]) + qC.y*bf2f(k1[1]) + qC.z*bf2f(k1[2]) + qC.w*bf2f(k1[3])
          + qD.x*bf2f(k1[4]) + qD.y*bf2f(k1[5]) + qD.z*bf2f(k1[6]) + qD.w*bf2f(k1[7]);
        d *= 0.25f;
        float mn = fmaxf(m, d);
        float al = __expf(m - mn);
        float a  = __expf(d - mn);
        m = mn;
        ss = ss*al + a;
        const short* vp = kvbf + t2*KVROW + 64 + h*16;
        bf16x8 v0 = *(const bf16x8*)vp;
        bf16x8 v1 = *(const bf16x8*)(vp + 8);
        oa0.x = oa0.x*al + a*bf2f(v0[0]); oa0.y = oa0.y*al + a*bf2f(v0[1]);
        oa0.z = oa0.z*al + a*bf2f(v0[2]); oa0.w = oa0.w*al + a*bf2f(v0[3]);
        oa1.x = oa1.x*al + a*bf2f(v0[4]); oa1.y = oa1.y*al + a*bf2f(v0[5]);
        oa1.z = oa1.z*al + a*bf2f(v0[6]); oa1.w = oa1.w*al + a*bf2f(v0[7]);
        oa2.x = oa2.x*al + a*bf2f(v1[0]); oa2.y = oa2.y*al + a*bf2f(v1[1]);
        oa2.z = oa2.z*al + a*bf2f(v1[2]); oa2.w = oa2.w*al + a*bf2f(v1[3]);
        oa3.x = oa3.x*al + a*bf2f(v1[4]); oa3.y = oa3.y*al + a*bf2f(v1[5]);
        oa3.z = oa3.z*al + a*bf2f(v1[6]); oa3.w = oa3.w*al + a*bf2f(v1[7]);
      }
      const float inv = 1.f/ss;
      bf16x8 w0, w1;
      w0[0]=(short)f2bf(oa0.x*inv); w0[1]=(short)f2bf(oa0.y*inv);
      w0[2]=(short)f2bf(oa0.z*inv); w0[3]=(short)f2bf(oa0.w*inv);
      w0[4]=(short)f2bf(oa1.x*inv); w0[5]=(short)f2bf(oa1.y*inv);
      w0[6]=(short)f2bf(oa1.z*inv); w0[7]=(short)f2bf(oa1.w*inv);
      w1[0]=(short)f2bf(oa2.x*inv); w1[1]=(short)f2bf(oa2.y*inv);
      w1[2]=(short)f2bf(oa2.z*inv); w1[3]=(short)f2bf(oa2.w*inv);
      w1[4]=(short)f2bf(oa3.x*inv); w1[5]=(short)f2bf(oa3.y*inv);
      w1[6]=(short)f2bf(oa3.z*inv); w1[7]=(short)f2bf(oa3.w*inv);
      short* op = obf + s*BROW + h*16;
      *(bf16x8*)op = w0;  *(bf16x8*)(op + 8) = w1;
    }
    __syncthreads();

    // ======== out-proj + residual -> yln (zone; qf/kvbf dead) ========
    {
      const short* ap = obf + n16*BROW + kg8;
      bf16x8 A00 = *(const bf16x8*)(ap);            bf16x8 A01 = *(const bf16x8*)(ap + 32);
      bf16x8 A10 = *(const bf16x8*)(ap + 16*BROW);  bf16x8 A11 = *(const bf16x8*)(ap + 16*BROW + 32);
      bf16x8 A20 = *(const bf16x8*)(ap + 32*BROW);  bf16x8 A21 = *(const bf16x8*)(ap + 32*BROW + 32);
      bf16x8 A30 = *(const bf16x8*)(ap + 48*BROW);  bf16x8 A31 = *(const bf16x8*)(ap + 48*BROW + 32);
      const int nt = wid;
      const short* bp = wF + (size_t)(48 + l*8 + nt*2)*512 + lane*8;
      bf16x8 B0 = *(const bf16x8*)(bp);
      bf16x8 B1 = *(const bf16x8*)(bp + 512);
      f32x4 c0={0,0,0,0}, c1={0,0,0,0}, c2={0,0,0,0}, c3={0,0,0,0};
      c0 = __builtin_amdgcn_mfma_f32_16x16x32_bf16(A00, B0, c0, 0,0,0);
      c0 = __builtin_amdgcn_mfma_f32_16x16x32_bf16(A01, B1, c0, 0,0,0);
      c1 = __builtin_amdgcn_mfma_f32_16x16x32_bf16(A10, B0, c1, 0,0,0);
      c1 = __builtin_amdgcn_mfma_f32_16x16x32_bf16(A11, B1, c1, 0,0,0);
      c2 = __builtin_amdgcn_mfma_f32_16x16x32_bf16(A20, B0, c2, 0,0,0);
      c2 = __builtin_amdgcn_mfma_f32_16x16x32_bf16(A21, B1, c2, 0,0,0);
      c3 = __builtin_amdgcn_mfma_f32_16x16x32_bf16(A30, B0, c3, 0,0,0);
      c3 = __builtin_amdgcn_mfma_f32_16x16x32_bf16(A31, B1, c3, 0,0,0);
      const int c = nt*16 + n16;
      const float bias = out_b[l*64 + c];
      #pragma unroll
      for (int r = 0; r < 4; ++r) {
        int m0 = mrow + r;
        yln[m0*68 + c] = xf[m0*64 + c] + bias + c0[r];
        if (m0+16 < SHORTN) yln[(m0+16)*68 + c] = xf[(m0+16)*64 + c] + bias + c1[r];
        if (m0+32 < SHORTN) yln[(m0+32)*68 + c] = xf[(m0+32)*64 + c] + bias + c2[r];
        if (m0+48 < SHORTN) yln[(m0+48)*68 + c] = xf[(m0+48)*64 + c] + bias + c3[r];
      }
      // zero f1bf pad rows [50,64): bytes 13600..17407, disjoint from yln
      for (int idx = tid; idx < 14*F1ROW; idx += 256) f1bf[50*F1ROW + idx] = 0;
    }
    __syncthreads();

    // ======== LN1: yln -> xf, xbf ========
    {
      const float g = ln1_g[l*64 + lane], bb = ln1_b[l*64 + lane];
      for (int s = wid; s < SHORTN; s += 4) {
        float y = yln[s*68 + lane];
        float mean = wave_sum(y) * (1.f/64.f);
        float dv = y - mean;
        float var = wave_sum(dv*dv) * (1.f/64.f);
        float r = dv / sqrtf(var + 1e-5f) * g + bb;
        xf[s*64 + lane] = r;
        xbf[s*BROW + lane] = (short)f2bf(r);
      }
    }
    __syncthreads();

    // ======== ff1 -> f1bf (zone; yln dead) ========
    {
      const short* ap = xbf + n16*BROW + kg8;
      bf16x8 A00 = *(const bf16x8*)(ap);            bf16x8 A01 = *(const bf16x8*)(ap + 32);
      bf16x8 A10 = *(const bf16x8*)(ap + 16*BROW);  bf16x8 A11 = *(const bf16x8*)(ap + 16*BROW + 32);
      bf16x8 A20 = *(const bf16x8*)(ap + 32*BROW);  bf16x8 A21 = *(const bf16x8*)(ap + 32*BROW + 32);
      bf16x8 A30 = *(const bf16x8*)(ap + 48*BROW);  bf16x8 A31 = *(const bf16x8*)(ap + 48*BROW + 32);
      #pragma unroll
      for (int t = 0; t < 2; ++t) {
        const int nt = wid*2 + t;
        const short* bp = wF + (size_t)(64 + l*16 + nt*2)*512 + lane*8;
        bf16x8 B0 = *(const bf16x8*)(bp);
        bf16x8 B1 = *(const bf16x8*)(bp + 512);
        f32x4 c0={0,0,0,0}, c1={0,0,0,0}, c2={0,0,0,0}, c3={0,0,0,0};
        c0 = __builtin_amdgcn_mfma_f32_16x16x32_bf16(A00, B0, c0, 0,0,0);
        c0 = __builtin_amdgcn_mfma_f32_16x16x32_bf16(A01, B1, c0, 0,0,0);
        c1 = __builtin_amdgcn_mfma_f32_16x16x32_bf16(A10, B0, c1, 0,0,0);
        c1 = __builtin_amdgcn_mfma_f32_16x16x32_bf16(A11, B1, c1, 0,0,0);
        c2 = __builtin_amdgcn_mfma_f32_16x16x32_bf16(A20, B0, c2, 0,0,0);
        c2 = __builtin_amdgcn_mfma_f32_16x16x32_bf16(A21, B1, c2, 0,0,0);
        c3 = __builtin_amdgcn_mfma_f32_16x16x32_bf16(A30, B0, c3, 0,0,0);
        c3 = __builtin_amdgcn_mfma_f32_16x16x32_bf16(A31, B1, c3, 0,0,0);
        const int c = nt*16 + n16;
        const float bias = ff1_b[l*128 + c];
        #pragma unroll
        for (int r = 0; r < 4; ++r) {
          int m0 = mrow + r;
          f1bf[m0*F1ROW + c] = (short)f2bf(fmaxf(c0[r] + bias, 0.f));
          if (m0+16 < SHORTN) f1bf[(m0+16)*F1ROW + c] = (short)f2bf(fmaxf(c1[r] + bias, 0.f));
          if (m0+32 < SHORTN) f1bf[(m0+32)*F1ROW + c] = (short)f2bf(fmaxf(c2[r] + bias, 0.f));
          if (m0+48 < SHORTN) f1bf[(m0+48)*F1ROW + c] = (short)f2bf(fmaxf(c3[r] + bias, 0.f));
        }
      }
    }
    __syncthreads();

    // ======== ff2 (K=128) -> yln (after sync; f1bf dead) ========
    {
      const int nt = wid;
      f32x4 c0={0,0,0,0}, c1={0,0,0,0}, c2={0,0,0,0}, c3={0,0,0,0};
      #pragma unroll
      for (int kc = 0; kc < 4; ++kc) {
        const short* ap = f1bf + n16*F1ROW + kc*32 + kg8;
        bf16x8 A0 = *(const bf16x8*)(ap);
        bf16x8 A1 = *(const bf16x8*)(ap + 16*F1ROW);
        bf16x8 A2 = *(const bf16x8*)(ap + 32*F1ROW);
        bf16x8 A3 = *(const bf16x8*)(ap + 48*F1ROW);
        const short* bp = wF + (size_t)(96 + l*16 + nt*4 + kc)*512 + lane*8;
        bf16x8 B = *(const bf16x8*)(bp);
        c0 = __builtin_amdgcn_mfma_f32_16x16x32_bf16(A0, B, c0, 0,0,0);
        c1 = __builtin_amdgcn_mfma_f32_16x16x32_bf16(A1, B, c1, 0,0,0);
        c2 = __builtin_amdgcn_mfma_f32_16x16x32_bf16(A2, B, c2, 0,0,0);
        c3 = __builtin_amdgcn_mfma_f32_16x16x32_bf16(A3, B, c3, 0,0,0);
      }
      __syncthreads();
      const int c = nt*16 + n16;
      const float bias = ff2_b[l*64 + c];
      #pragma unroll
      for (int r = 0; r < 4; ++r) {
        int m0 = mrow + r;
        yln[m0*68 + c] = xf[m0*64 + c] + bias + c0[r];
        if (m0+16 < SHORTN) yln[(m0+16)*68 + c] = xf[(m0+16)*64 + c] + bias + c1[r];
        if (m0+32 < SHORTN) yln[(m0+32)*68 + c] = xf[(m0+32)*64 + c] + bias + c2[r];
        if (m0+48 < SHORTN) yln[(m0+48)*68 + c] = xf[(m0+48)*64 + c] + bias + c3[r];
      }
    }
    __syncthreads();

    // ======== LN2: yln -> xf, xbf ========
    {
      const float g = ln2_g[l*64 + lane], bb = ln2_b[l*64 + lane];
      for (int s = wid; s < SHORTN; s += 4) {
        float y = yln[s*68 + lane];
        float mean = wave_sum(y) * (1.f/64.f);
        float dv = y - mean;
        float var = wave_sum(dv*dv) * (1.f/64.f);
        float r = dv / sqrtf(var + 1e-5f) * g + bb;
        xf[s*64 + lane] = r;
        xbf[s*BROW + lane] = (short)f2bf(r);
      }
    }
    __syncthreads();
  }

  // ---- mean over sequence (qf region free) ----
  float acc = 0.f;
  for (int s = wid; s < SHORTN; s += 4) acc += xf[s*64 + lane];
  qf[wid*64 + lane] = acc;
  __syncthreads();
  if (wid == 0)
    bst_out[b*64 + lane] = (qf[lane] + qf[64+lane] + qf[128+lane] + qf[192+lane]) * (1.f/50.f);
}

// ===========================================================================
// Fusion MLP. (unchanged)
// ===========================================================================
__global__ __launch_bounds__(256) void fusion_kernel(
    const float* __restrict__ user, const float* __restrict__ hard,
    const float* __restrict__ soft, const float* __restrict__ bst,
    const float* __restrict__ w1, const float* __restrict__ b1,
    const float* __restrict__ w2, const float* __restrict__ b2,
    const float* __restrict__ w3, const float* __restrict__ b3,
    float* __restrict__ out)
{
  __shared__ __align__(16) float comb[256];
  __shared__ __align__(16) float h1[256];
  __shared__ __align__(16) float h2[128];
  const int b = blockIdx.x, tid = threadIdx.x;
  if (tid < 64)       comb[tid] = user[b*64 + tid];
  else if (tid < 128) comb[tid] = hard[b*64 + tid - 64];
  else if (tid < 192) comb[tid] = soft[b*64 + tid - 128];
  else                comb[tid] = bst[b*64 + tid - 192];
  __syncthreads();
  h1[tid] = fmaxf(b1[tid] + dotN<256>(w1 + tid*256, comb), 0.f);
  __syncthreads();
  if (tid < 128) h2[tid] = fmaxf(b2[tid] + dotN<256>(w2 + tid*256, h1), 0.f);
  __syncthreads();
  if (tid < 64) {
    float p = w3[tid]*h2[tid] + w3[tid+64]*h2[tid+64];
    p = wave_sum(p);
    if (tid == 0) out[b] = p + b3[0];
  }
}

extern "C" void kernel_launch(void* const* d_in, const int* in_sizes, int n_in,
                              void* d_out, int out_size, void* d_ws, size_t ws_size,
                              hipStream_t stream) {
  const float* user_features  = (const float*)d_in[0];
  const int*   target_item_id = (const int*)  d_in[1];
  const int*   short_hist_ids = (const int*)  d_in[2];
  const int*   long_hist_ids  = (const int*)  d_in[3];
  const float* item_emb       = (const float*)d_in[4];
  const float* tproj_w  = (const float*)d_in[5];
  const float* tproj_b  = (const float*)d_in[6];
  const float* attn_w1  = (const float*)d_in[7];
  const float* attn_b1  = (const float*)d_in[8];
  const float* attn_w2  = (const float*)d_in[9];
  const float* attn_b2  = (const float*)d_in[10];
  const float* hash_emb = (const float*)d_in[11];
  const float* sdim_w   = (const float*)d_in[12];
  const float* sdim_b   = (const float*)d_in[13];
  const float* tf_qkv_w = (const float*)d_in[14];
  const float* tf_qkv_b = (const float*)d_in[15];
  const float* tf_out_w = (const float*)d_in[16];
  const float* tf_out_b = (const float*)d_in[17];
  const float* tf_ln1_g = (const float*)d_in[18];
  const float* tf_ln1_b = (const float*)d_in[19];
  const float* tf_ff1_w = (const float*)d_in[20];
  const float* tf_ff1_b = (const float*)d_in[21];
  const float* tf_ff2_w = (const float*)d_in[22];
  const float* tf_ff2_b = (const float*)d_in[23];
  const float* tf_ln2_g = (const float*)d_in[24];
  const float* tf_ln2_b = (const float*)d_in[25];
  const float* fus_w1   = (const float*)d_in[26];
  const float* fus_b1   = (const float*)d_in[27];
  const float* fus_w2   = (const float*)d_in[28];
  const float* fus_b2   = (const float*)d_in[29];
  const float* fus_w3   = (const float*)d_in[30];
  const float* fus_b3   = (const float*)d_in[31];

  const int emb_elems = in_sizes[4];         // (NUM_ITEMS+1)*64

  float* ws = (float*)d_ws;
  float* hard = ws;                    // NB*64
  float* soft = hard + NB*64;          // NB*64
  float* bst  = soft + NB*64;          // NB*64
  float* scores_ws = bst + NB*64;      // NB*1000
  float* partA = scores_ws + NB*LONGN; // NB*2*64
  float* partH = partA + NB*2*64;      // NB*2*64
  short* wF    = (short*)(partH + NB*2*64); // 65536 shorts (128 KB)
  short* embT  = wF + 65536;                // emb_elems shorts

  const size_t base_bytes = (size_t)(3*NB*64 + NB*LONGN + 2*NB*2*64) * 4 + 65536*2;
  const size_t need_bytes = base_bytes + (size_t)emb_elems * 2;
  const int use_bf16 = (ws_size >= need_bytes) ? 1 : 0;

  bst_prep_kernel<<<32, 256, 0, stream>>>(tf_qkv_w, tf_out_w, tf_ff1_w, tf_ff2_w, wF);
  if (use_bf16) {
    const int n8 = emb_elems / 8;
    emb_prep_kernel<<<(n8 + 255)/256, 256, 0, stream>>>(item_emb, embT, n8);
  }
  hard_scores_kernel<<<2*NB, 256, 0, stream>>>(target_item_id, long_hist_ids,
      item_emb, embT, use_bf16, tproj_w, tproj_b, attn_w1, attn_b1, attn_w2, attn_b2,
      hash_emb, scores_ws, partA, partH);
  hard_finish_kernel<<<NB, 256, 0, stream>>>(long_hist_ids, item_emb,
      sdim_w, sdim_b, scores_ws, partA, partH, hard, soft);
  bst_kernel<<<NB, 256, 0, stream>>>(short_hist_ids, item_emb, wF,
      tf_qkv_b, tf_out_b, tf_ln1_g, tf_ln1_b, tf_ff1_b, tf_ff2_b,
      tf_ln2_g, tf_ln2_b, bst);
  fusion_kernel<<<NB, 256, 0, stream>>>(user_features, hard, soft, bst,
      fus_w1, fus_b1, fus_w2, fus_b2, fus_w3, fus_b3, (float*)d_out);
}

// Round 12
// 168.271 us; speedup vs baseline: 1.3269x; 1.1985x over previous
//
#include <hip/hip_runtime.h>
#include <math.h>

#define NB 512
#define LONGN 1000
#define SHORTN 50
#define TOPKN 50
#define HALFN 500
#define NG 8          // item-groups per hard block
#define EROW 72       // hard-path bf16 LDS row stride (shorts)
#define BROW 72       // bst bf16 row stride (shorts) for xbf/obf
#define F1ROW 136     // bst bf16 row stride for ff1 output (128+8)

typedef __attribute__((ext_vector_type(8))) short bf16x8;
typedef __attribute__((ext_vector_type(4))) float f32x4;

__device__ __forceinline__ float dot4(float4 a, float4 b) {
  return a.x*b.x + a.y*b.y + a.z*b.z + a.w*b.w;
}

template<int N>
__device__ __forceinline__ float dotN(const float* w, const float* x) {
  const float4* w4 = (const float4*)w;
  const float4* x4 = (const float4*)x;
  float a0 = 0.f, a1 = 0.f, a2 = 0.f, a3 = 0.f;
  #pragma unroll
  for (int k = 0; k < N/4; k += 4) {
    a0 += dot4(w4[k],   x4[k]);
    a1 += dot4(w4[k+1], x4[k+1]);
    a2 += dot4(w4[k+2], x4[k+2]);
    a3 += dot4(w4[k+3], x4[k+3]);
  }
  return (a0 + a1) + (a2 + a3);
}

__device__ __forceinline__ float wave_sum(float v) {
  #pragma unroll
  for (int off = 32; off > 0; off >>= 1) v += __shfl_xor(v, off);
  return v;
}
__device__ __forceinline__ float wave_max(float v) {
  #pragma unroll
  for (int off = 32; off > 0; off >>= 1) v = fmaxf(v, __shfl_xor(v, off));
  return v;
}

__device__ __forceinline__ unsigned short f2bf(float x) {  // RNE fp32->bf16
  unsigned u = __float_as_uint(x);
  return (unsigned short)((u + 0x7fffu + ((u >> 16) & 1u)) >> 16);
}

// ===========================================================================
// K1 (MFMA): hard-search scores. (R9 version, f32 gather)
// ===========================================================================
__global__ __launch_bounds__(256, 3) void hard_scores_kernel(
    const int* __restrict__ target_item_id,
    const int* __restrict__ long_hist_ids,
    const float* __restrict__ item_emb,
    const float* __restrict__ tproj_w, const float* __restrict__ tproj_b,
    const float* __restrict__ attn_w1, const float* __restrict__ attn_b1,
    const float* __restrict__ attn_w2, const float* __restrict__ attn_b2,
    const float* __restrict__ hash_emb,
    float* __restrict__ scores_ws, float* __restrict__ partA,
    float* __restrict__ partH)
{
  __shared__ __align__(16) short Abf[64*EROW];
  __shared__ __align__(16) short Ebuf[2][64*EROW];
  __shared__ __align__(16) float tv[64];
  __shared__ __align__(16) float te[64];
  __shared__ __align__(16) float2 cw[64];
  __shared__ int idsL[HALFN];
  __shared__ __align__(16) float redE[4*64];

  const int bid = blockIdx.x;
  const int b = bid >> 1, half = bid & 1;
  const int base = half * HALFN;
  const int tid = threadIdx.x;
  const int wid = tid >> 6, lane = tid & 63;

  if (tid < 64) tv[tid] = item_emb[target_item_id[b]*64 + tid];
  for (int l = tid; l < HALFN; l += 256) idsL[l] = long_hist_ids[b*LONGN + base + l];
  __syncthreads();
  if (tid < 64) te[tid] = tproj_b[tid] + dotN<64>(tproj_w + tid*64, tv);
  __syncthreads();
  if (tid < 64) {
    float c = attn_b1[tid] + dotN<64>(attn_w1 + tid*192, te);
    cw[tid] = make_float2(c, attn_w2[tid]);
  }
  for (int idx = tid; idx < 4096; idx += 256) {
    int i = idx >> 6, j = idx & 63;
    Abf[i*EROW + j] = (short)f2bf(attn_w1[i*192 + 64 + j] + attn_w1[i*192 + 128 + j]*te[j]);
  }
  __syncthreads();

  bf16x8 a00,a01,a10,a11,a20,a21,a30,a31;
  {
    const short* ap = Abf + (lane & 15)*EROW + ((lane >> 4) << 3);
    a00 = *(const bf16x8*)(ap +  0*EROW);  a01 = *(const bf16x8*)(ap +  0*EROW + 32);
    a10 = *(const bf16x8*)(ap + 16*EROW);  a11 = *(const bf16x8*)(ap + 16*EROW + 32);
    a20 = *(const bf16x8*)(ap + 32*EROW);  a21 = *(const bf16x8*)(ap + 32*EROW + 32);
    a30 = *(const bf16x8*)(ap + 48*EROW);  a31 = *(const bf16x8*)(ap + 48*EROW + 32);
  }

  const float b2s = attn_b2[0];
  const int it_g = tid >> 2;
  const int dimg = (tid & 3) * 16;

  float4 sE0 = {0,0,0,0}, sE1 = {0,0,0,0}, sE2 = {0,0,0,0}, sE3 = {0,0,0,0};

  {
    const float4* ep = (const float4*)(item_emb + (size_t)idsL[it_g]*64 + dimg);
    float4 r0 = ep[0], r1 = ep[1], r2 = ep[2], r3 = ep[3];
    sE0.x+=r0.x; sE0.y+=r0.y; sE0.z+=r0.z; sE0.w+=r0.w;
    sE1.x+=r1.x; sE1.y+=r1.y; sE1.z+=r1.z; sE1.w+=r1.w;
    sE2.x+=r2.x; sE2.y+=r2.y; sE2.z+=r2.z; sE2.w+=r2.w;
    sE3.x+=r3.x; sE3.y+=r3.y; sE3.z+=r3.z; sE3.w+=r3.w;
    bf16x8 w0, w1;
    w0[0]=(short)f2bf(r0.x); w0[1]=(short)f2bf(r0.y); w0[2]=(short)f2bf(r0.z); w0[3]=(short)f2bf(r0.w);
    w0[4]=(short)f2bf(r1.x); w0[5]=(short)f2bf(r1.y); w0[6]=(short)f2bf(r1.z); w0[7]=(short)f2bf(r1.w);
    w1[0]=(short)f2bf(r2.x); w1[1]=(short)f2bf(r2.y); w1[2]=(short)f2bf(r2.z); w1[3]=(short)f2bf(r2.w);
    w1[4]=(short)f2bf(r3.x); w1[5]=(short)f2bf(r3.y); w1[6]=(short)f2bf(r3.z); w1[7]=(short)f2bf(r3.w);
    short* dst = &Ebuf[0][it_g*EROW + dimg];
    *(bf16x8*)dst = w0;  *(bf16x8*)(dst + 8) = w1;
  }
  __syncthreads();

  int buf = 0;
  for (int g = 0; g < NG; ++g) {
    float4 r0={0,0,0,0}, r1={0,0,0,0}, r2={0,0,0,0}, r3={0,0,0,0};
    const bool more = (g + 1 < NG);
    if (more) {
      const int gi = (g+1)*64 + it_g;
      if (gi < HALFN) {
        const float4* ep = (const float4*)(item_emb + (size_t)idsL[gi]*64 + dimg);
        r0 = ep[0]; r1 = ep[1]; r2 = ep[2]; r3 = ep[3];
      }
    }

    f32x4 acc0={0,0,0,0}, acc1={0,0,0,0}, acc2={0,0,0,0}, acc3={0,0,0,0};
    {
      const short* ep = &Ebuf[buf][(wid*16 + (lane & 15))*EROW + ((lane >> 4) << 3)];
      bf16x8 b0 = *(const bf16x8*)(ep);
      bf16x8 b1 = *(const bf16x8*)(ep + 32);
      acc0 = __builtin_amdgcn_mfma_f32_16x16x32_bf16(a00, b0, acc0, 0, 0, 0);
      acc0 = __builtin_amdgcn_mfma_f32_16x16x32_bf16(a01, b1, acc0, 0, 0, 0);
      acc1 = __builtin_amdgcn_mfma_f32_16x16x32_bf16(a10, b0, acc1, 0, 0, 0);
      acc1 = __builtin_amdgcn_mfma_f32_16x16x32_bf16(a11, b1, acc1, 0, 0, 0);
      acc2 = __builtin_amdgcn_mfma_f32_16x16x32_bf16(a20, b0, acc2, 0, 0, 0);
      acc2 = __builtin_amdgcn_mfma_f32_16x16x32_bf16(a21, b1, acc2, 0, 0, 0);
      acc3 = __builtin_amdgcn_mfma_f32_16x16x32_bf16(a30, b0, acc3, 0, 0, 0);
      acc3 = __builtin_amdgcn_mfma_f32_16x16x32_bf16(a31, b1, acc3, 0, 0, 0);
    }
    float p = 0.f;
    {
      const int rbase = (lane >> 4) << 2;
      #pragma unroll
      for (int r = 0; r < 4; ++r) {
        float2 c0 = cw[ 0 + rbase + r];
        float2 c1 = cw[16 + rbase + r];
        float2 c2 = cw[32 + rbase + r];
        float2 c3 = cw[48 + rbase + r];
        p += c0.y * fmaxf(acc0[r] + c0.x, 0.f);
        p += c1.y * fmaxf(acc1[r] + c1.x, 0.f);
        p += c2.y * fmaxf(acc2[r] + c2.x, 0.f);
        p += c3.y * fmaxf(acc3[r] + c3.x, 0.f);
      }
    }
    p += __shfl_xor(p, 16);
    p += __shfl_xor(p, 32);
    if (lane < 16) {
      const int gi = g*64 + wid*16 + lane;
      if (gi < HALFN) scores_ws[b*LONGN + base + gi] = b2s + p;
    }

    if (more) {
      sE0.x+=r0.x; sE0.y+=r0.y; sE0.z+=r0.z; sE0.w+=r0.w;
      sE1.x+=r1.x; sE1.y+=r1.y; sE1.z+=r1.z; sE1.w+=r1.w;
      sE2.x+=r2.x; sE2.y+=r2.y; sE2.z+=r2.z; sE2.w+=r2.w;
      sE3.x+=r3.x; sE3.y+=r3.y; sE3.z+=r3.z; sE3.w+=r3.w;
      bf16x8 w0, w1;
      w0[0]=(short)f2bf(r0.x); w0[1]=(short)f2bf(r0.y); w0[2]=(short)f2bf(r0.z); w0[3]=(short)f2bf(r0.w);
      w0[4]=(short)f2bf(r1.x); w0[5]=(short)f2bf(r1.y); w0[6]=(short)f2bf(r1.z); w0[7]=(short)f2bf(r1.w);
      w1[0]=(short)f2bf(r2.x); w1[1]=(short)f2bf(r2.y); w1[2]=(short)f2bf(r2.z); w1[3]=(short)f2bf(r2.w);
      w1[4]=(short)f2bf(r3.x); w1[5]=(short)f2bf(r3.y); w1[6]=(short)f2bf(r3.z); w1[7]=(short)f2bf(r3.w);
      short* dst = &Ebuf[buf ^ 1][it_g*EROW + dimg];
      *(bf16x8*)dst = w0;  *(bf16x8*)(dst + 8) = w1;
    }
    __syncthreads();
    buf ^= 1;
  }

  {
    float* red = (float*)&Ebuf[0][0];
    const int b17 = tid * 17;
    red[b17+ 0]=sE0.x; red[b17+ 1]=sE0.y; red[b17+ 2]=sE0.z; red[b17+ 3]=sE0.w;
    red[b17+ 4]=sE1.x; red[b17+ 5]=sE1.y; red[b17+ 6]=sE1.z; red[b17+ 7]=sE1.w;
    red[b17+ 8]=sE2.x; red[b17+ 9]=sE2.y; red[b17+10]=sE2.z; red[b17+11]=sE2.w;
    red[b17+12]=sE3.x; red[b17+13]=sE3.y; red[b17+14]=sE3.z; red[b17+15]=sE3.w;
    __syncthreads();
    if (tid < 64) {
      const int dg = tid >> 4, dw = tid & 15;
      float s = 0.f;
      for (int j = 0; j < 64; ++j) s += red[(j*4 + dg)*17 + dw];
      partA[bid*64 + tid] = s;
    }
  }

  {
    const int hl = lane >> 4, dd = lane & 15;
    const float* hb = hash_emb + hl*1024*16 + dd;
    float accH = 0.f;
    for (int l = wid; l < HALFN; l += 4)
      accH += hb[(idsL[l] & 1023)*16];
    redE[wid*64 + lane] = accH;
  }
  __syncthreads();
  if (wid == 0)
    partH[bid*64 + lane] = redE[lane] + redE[64+lane] + redE[128+lane] + redE[192+lane];
}

// ===========================================================================
// BST weight prep (unchanged).
// ===========================================================================
__global__ __launch_bounds__(256) void bst_prep_kernel(
    const float* __restrict__ qkv_w, const float* __restrict__ out_w,
    const float* __restrict__ ff1_w, const float* __restrict__ ff2_w,
    short* __restrict__ wF)
{
  const int t = blockIdx.x*256 + threadIdx.x;   // 8192 threads
  if (t >= 8192) return;
  const int fid = t >> 6, lane = t & 63;
  const int n16 = lane & 15, k8 = (lane >> 4) * 8;
  const float* src;
  if (fid < 48)      { int f=fid,    l=f/24, r=f%24, nt=r>>1, kc=r&1;
    src = qkv_w + l*12288 + (nt*16+n16)*64 + kc*32 + k8; }
  else if (fid < 64) { int f=fid-48, l=f>>3, r=f&7,  nt=r>>1, kc=r&1;
    src = out_w + l*4096 + (nt*16+n16)*64 + kc*32 + k8; }
  else if (fid < 96) { int f=fid-64, l=f>>4, r=f&15, nt=r>>1, kc=r&1;
    src = ff1_w + l*8192 + (nt*16+n16)*64 + kc*32 + k8; }
  else               { int f=fid-96, l=f>>4, r=f&15, nt=r>>2, kc=r&3;
    src = ff2_w + l*8192 + (nt*16+n16)*128 + kc*32 + k8; }
  short* dst = wF + fid*512 + lane*8;
  #pragma unroll
  for (int j = 0; j < 8; ++j) dst[j] = (short)f2bf(src[j]);
}

// ===========================================================================
// BST transformer (R9 MFMA version, f32 k/v).
// ===========================================================================
__global__ __launch_bounds__(256) void bst_kernel(
    const int* __restrict__ short_ids, const float* __restrict__ item_emb,
    const short* __restrict__ wF,
    const float* __restrict__ qkv_b, const float* __restrict__ out_b,
    const float* __restrict__ ln1_g, const float* __restrict__ ln1_b,
    const float* __restrict__ ff1_b, const float* __restrict__ ff2_b,
    const float* __restrict__ ln2_g, const float* __restrict__ ln2_b,
    float* __restrict__ bst_out)
{
  __shared__ __align__(16) float xf[SHORTN*64];
  __shared__ __align__(16) short xbf[64*BROW];
  __shared__ __align__(16) float qf[SHORTN*68];
  __shared__ __align__(16) float arena[SHORTN*132];
  __shared__ __align__(16) short obf[64*BROW];

  short* f1bf = (short*)arena;

  const int b = blockIdx.x, tid = threadIdx.x;
  const int wid = tid >> 6, lane = tid & 63;
  const int n16 = lane & 15;
  const int kg8 = (lane >> 4) << 3;
  const int mrow = (lane >> 4) << 2;

  for (int idx = tid; idx < SHORTN*64; idx += 256) {
    int s = idx >> 6, j = idx & 63;
    float v = item_emb[short_ids[b*SHORTN + s]*64 + j];
    xf[idx] = v;
    xbf[s*BROW + j] = (short)f2bf(v);
  }
  for (int idx = tid; idx < 14*BROW; idx += 256) {
    xbf[50*BROW + idx] = 0;
    obf[50*BROW + idx] = 0;
  }
  __syncthreads();

  for (int l = 0; l < 2; ++l) {
    // ======== qkv ========
    {
      const short* ap = xbf + n16*BROW + kg8;
      bf16x8 A00 = *(const bf16x8*)(ap);            bf16x8 A01 = *(const bf16x8*)(ap + 32);
      bf16x8 A10 = *(const bf16x8*)(ap + 16*BROW);  bf16x8 A11 = *(const bf16x8*)(ap + 16*BROW + 32);
      bf16x8 A20 = *(const bf16x8*)(ap + 32*BROW);  bf16x8 A21 = *(const bf16x8*)(ap + 32*BROW + 32);
      bf16x8 A30 = *(const bf16x8*)(ap + 48*BROW);  bf16x8 A31 = *(const bf16x8*)(ap + 48*BROW + 32);
      #pragma unroll
      for (int t = 0; t < 3; ++t) {
        const int nt = wid*3 + t;
        const short* bp = wF + (size_t)(l*24 + nt*2)*512 + lane*8;
        bf16x8 B0 = *(const bf16x8*)(bp);
        bf16x8 B1 = *(const bf16x8*)(bp + 512);
        f32x4 c0={0,0,0,0}, c1={0,0,0,0}, c2={0,0,0,0}, c3={0,0,0,0};
        c0 = __builtin_amdgcn_mfma_f32_16x16x32_bf16(A00, B0, c0, 0,0,0);
        c0 = __builtin_amdgcn_mfma_f32_16x16x32_bf16(A01, B1, c0, 0,0,0);
        c1 = __builtin_amdgcn_mfma_f32_16x16x32_bf16(A10, B0, c1, 0,0,0);
        c1 = __builtin_amdgcn_mfma_f32_16x16x32_bf16(A11, B1, c1, 0,0,0);
        c2 = __builtin_amdgcn_mfma_f32_16x16x32_bf16(A20, B0, c2, 0,0,0);
        c2 = __builtin_amdgcn_mfma_f32_16x16x32_bf16(A21, B1, c2, 0,0,0);
        c3 = __builtin_amdgcn_mfma_f32_16x16x32_bf16(A30, B0, c3, 0,0,0);
        c3 = __builtin_amdgcn_mfma_f32_16x16x32_bf16(A31, B1, c3, 0,0,0);
        const int c = nt*16 + n16;
        const float bias = qkv_b[l*192 + c];
        #pragma unroll
        for (int r = 0; r < 4; ++r) {
          int m0 = mrow + r;
          float v0 = c0[r] + bias;
          float v1 = c1[r] + bias;
          float v2 = c2[r] + bias;
          float v3 = c3[r] + bias;
          if (c < 64) {
            qf[m0*68 + c] = v0;
            if (m0+16 < SHORTN) qf[(m0+16)*68 + c] = v1;
            if (m0+32 < SHORTN) qf[(m0+32)*68 + c] = v2;
            if (m0+48 < SHORTN) qf[(m0+48)*68 + c] = v3;
          } else {
            const int cc = c - 64;
            arena[m0*132 + cc] = v0;
            if (m0+16 < SHORTN) arena[(m0+16)*132 + cc] = v1;
            if (m0+32 < SHORTN) arena[(m0+32)*132 + cc] = v2;
            if (m0+48 < SHORTN) arena[(m0+48)*132 + cc] = v3;
          }
        }
      }
    }
    __syncthreads();

    // ======== attention: f32 online softmax ========
    if (tid < 4*SHORTN) {
      const int h = tid / SHORTN, s = tid - h*SHORTN;
      const float4* qp = (const float4*)(qf + s*68 + h*16);
      const float4 qA = qp[0], qB2 = qp[1], qC = qp[2], qD = qp[3];
      float m = -INFINITY, ss = 0.f;
      float4 oa0 = {0,0,0,0}, oa1 = {0,0,0,0}, oa2 = {0,0,0,0}, oa3 = {0,0,0,0};
      for (int t2 = 0; t2 < SHORTN; ++t2) {
        const float4* kp = (const float4*)(arena + t2*132 + h*16);
        float d = dot4(qA,kp[0]) + dot4(qB2,kp[1]) + dot4(qC,kp[2]) + dot4(qD,kp[3]);
        d *= 0.25f;
        float mn = fmaxf(m, d);
        float al = __expf(m - mn);
        float a  = __expf(d - mn);
        m = mn;
        ss = ss*al + a;
        const float4* vp = (const float4*)(arena + t2*132 + 64 + h*16);
        float4 v0 = vp[0], v1 = vp[1], v2 = vp[2], v3 = vp[3];
        oa0.x = oa0.x*al + a*v0.x; oa0.y = oa0.y*al + a*v0.y;
        oa0.z = oa0.z*al + a*v0.z; oa0.w = oa0.w*al + a*v0.w;
        oa1.x = oa1.x*al + a*v1.x; oa1.y = oa1.y*al + a*v1.y;
        oa1.z = oa1.z*al + a*v1.z; oa1.w = oa1.w*al + a*v1.w;
        oa2.x = oa2.x*al + a*v2.x; oa2.y = oa2.y*al + a*v2.y;
        oa2.z = oa2.z*al + a*v2.z; oa2.w = oa2.w*al + a*v2.w;
        oa3.x = oa3.x*al + a*v3.x; oa3.y = oa3.y*al + a*v3.y;
        oa3.z = oa3.z*al + a*v3.z; oa3.w = oa3.w*al + a*v3.w;
      }
      const float inv = 1.f/ss;
      bf16x8 w0, w1;
      w0[0]=(short)f2bf(oa0.x*inv); w0[1]=(short)f2bf(oa0.y*inv);
      w0[2]=(short)f2bf(oa0.z*inv); w0[3]=(short)f2bf(oa0.w*inv);
      w0[4]=(short)f2bf(oa1.x*inv); w0[5]=(short)f2bf(oa1.y*inv);
      w0[6]=(short)f2bf(oa1.z*inv); w0[7]=(short)f2bf(oa1.w*inv);
      w1[0]=(short)f2bf(oa2.x*inv); w1[1]=(short)f2bf(oa2.y*inv);
      w1[2]=(short)f2bf(oa2.z*inv); w1[3]=(short)f2bf(oa2.w*inv);
      w1[4]=(short)f2bf(oa3.x*inv); w1[5]=(short)f2bf(oa3.y*inv);
      w1[6]=(short)f2bf(oa3.z*inv); w1[7]=(short)f2bf(oa3.w*inv);
      short* op = obf + s*BROW + h*16;
      *(bf16x8*)op = w0;  *(bf16x8*)(op + 8) = w1;
    }
    __syncthreads();

    // ======== out-proj + y ========
    {
      const short* ap = obf + n16*BROW + kg8;
      bf16x8 A00 = *(const bf16x8*)(ap);            bf16x8 A01 = *(const bf16x8*)(ap + 32);
      bf16x8 A10 = *(const bf16x8*)(ap + 16*BROW);  bf16x8 A11 = *(const bf16x8*)(ap + 16*BROW + 32);
      bf16x8 A20 = *(const bf16x8*)(ap + 32*BROW);  bf16x8 A21 = *(const bf16x8*)(ap + 32*BROW + 32);
      bf16x8 A30 = *(const bf16x8*)(ap + 48*BROW);  bf16x8 A31 = *(const bf16x8*)(ap + 48*BROW + 32);
      const int nt = wid;
      const short* bp = wF + (size_t)(48 + l*8 + nt*2)*512 + lane*8;
      bf16x8 B0 = *(const bf16x8*)(bp);
      bf16x8 B1 = *(const bf16x8*)(bp + 512);
      f32x4 c0={0,0,0,0}, c1={0,0,0,0}, c2={0,0,0,0}, c3={0,0,0,0};
      c0 = __builtin_amdgcn_mfma_f32_16x16x32_bf16(A00, B0, c0, 0,0,0);
      c0 = __builtin_amdgcn_mfma_f32_16x16x32_bf16(A01, B1, c0, 0,0,0);
      c1 = __builtin_amdgcn_mfma_f32_16x16x32_bf16(A10, B0, c1, 0,0,0);
      c1 = __builtin_amdgcn_mfma_f32_16x16x32_bf16(A11, B1, c1, 0,0,0);
      c2 = __builtin_amdgcn_mfma_f32_16x16x32_bf16(A20, B0, c2, 0,0,0);
      c2 = __builtin_amdgcn_mfma_f32_16x16x32_bf16(A21, B1, c2, 0,0,0);
      c3 = __builtin_amdgcn_mfma_f32_16x16x32_bf16(A30, B0, c3, 0,0,0);
      c3 = __builtin_amdgcn_mfma_f32_16x16x32_bf16(A31, B1, c3, 0,0,0);
      const int c = nt*16 + n16;
      const float bias = out_b[l*64 + c];
      #pragma unroll
      for (int r = 0; r < 4; ++r) {
        int m0 = mrow + r;
        arena[m0*68 + c] = xf[m0*64 + c] + bias + c0[r];
        if (m0+16 < SHORTN) arena[(m0+16)*68 + c] = xf[(m0+16)*64 + c] + bias + c1[r];
        if (m0+32 < SHORTN) arena[(m0+32)*68 + c] = xf[(m0+32)*64 + c] + bias + c2[r];
        if (m0+48 < SHORTN) arena[(m0+48)*68 + c] = xf[(m0+48)*64 + c] + bias + c3[r];
      }
      for (int idx = tid; idx < 14*F1ROW; idx += 256) f1bf[50*F1ROW + idx] = 0;
    }
    __syncthreads();

    // ======== LN1 ========
    {
      const float g = ln1_g[l*64 + lane], bb = ln1_b[l*64 + lane];
      for (int s = wid; s < SHORTN; s += 4) {
        float y = arena[s*68 + lane];
        float mean = wave_sum(y) * (1.f/64.f);
        float dv = y - mean;
        float var = wave_sum(dv*dv) * (1.f/64.f);
        float r = dv / sqrtf(var + 1e-5f) * g + bb;
        xf[s*64 + lane] = r;
        xbf[s*BROW + lane] = (short)f2bf(r);
      }
    }
    __syncthreads();

    // ======== ff1 ========
    {
      const short* ap = xbf + n16*BROW + kg8;
      bf16x8 A00 = *(const bf16x8*)(ap);            bf16x8 A01 = *(const bf16x8*)(ap + 32);
      bf16x8 A10 = *(const bf16x8*)(ap + 16*BROW);  bf16x8 A11 = *(const bf16x8*)(ap + 16*BROW + 32);
      bf16x8 A20 = *(const bf16x8*)(ap + 32*BROW);  bf16x8 A21 = *(const bf16x8*)(ap + 32*BROW + 32);
      bf16x8 A30 = *(const bf16x8*)(ap + 48*BROW);  bf16x8 A31 = *(const bf16x8*)(ap + 48*BROW + 32);
      #pragma unroll
      for (int t = 0; t < 2; ++t) {
        const int nt = wid*2 + t;
        const short* bp = wF + (size_t)(64 + l*16 + nt*2)*512 + lane*8;
        bf16x8 B0 = *(const bf16x8*)(bp);
        bf16x8 B1 = *(const bf16x8*)(bp + 512);
        f32x4 c0={0,0,0,0}, c1={0,0,0,0}, c2={0,0,0,0}, c3={0,0,0,0};
        c0 = __builtin_amdgcn_mfma_f32_16x16x32_bf16(A00, B0, c0, 0,0,0);
        c0 = __builtin_amdgcn_mfma_f32_16x16x32_bf16(A01, B1, c0, 0,0,0);
        c1 = __builtin_amdgcn_mfma_f32_16x16x32_bf16(A10, B0, c1, 0,0,0);
        c1 = __builtin_amdgcn_mfma_f32_16x16x32_bf16(A11, B1, c1, 0,0,0);
        c2 = __builtin_amdgcn_mfma_f32_16x16x32_bf16(A20, B0, c2, 0,0,0);
        c2 = __builtin_amdgcn_mfma_f32_16x16x32_bf16(A21, B1, c2, 0,0,0);
        c3 = __builtin_amdgcn_mfma_f32_16x16x32_bf16(A30, B0, c3, 0,0,0);
        c3 = __builtin_amdgcn_mfma_f32_16x16x32_bf16(A31, B1, c3, 0,0,0);
        const int c = nt*16 + n16;
        const float bias = ff1_b[l*128 + c];
        #pragma unroll
        for (int r = 0; r < 4; ++r) {
          int m0 = mrow + r;
          f1bf[m0*F1ROW + c] = (short)f2bf(fmaxf(c0[r] + bias, 0.f));
          if (m0+16 < SHORTN) f1bf[(m0+16)*F1ROW + c] = (short)f2bf(fmaxf(c1[r] + bias, 0.f));
          if (m0+32 < SHORTN) f1bf[(m0+32)*F1ROW + c] = (short)f2bf(fmaxf(c2[r] + bias, 0.f));
          if (m0+48 < SHORTN) f1bf[(m0+48)*F1ROW + c] = (short)f2bf(fmaxf(c3[r] + bias, 0.f));
        }
      }
    }
    __syncthreads();

    // ======== ff2 ========
    {
      const int nt = wid;
      f32x4 c0={0,0,0,0}, c1={0,0,0,0}, c2={0,0,0,0}, c3={0,0,0,0};
      #pragma unroll
      for (int kc = 0; kc < 4; ++kc) {
        const short* ap = f1bf + n16*F1ROW + kc*32 + kg8;
        bf16x8 A0 = *(const bf16x8*)(ap);
        bf16x8 A1 = *(const bf16x8*)(ap + 16*F1ROW);
        bf16x8 A2 = *(const bf16x8*)(ap + 32*F1ROW);
        bf16x8 A3 = *(const bf16x8*)(ap + 48*F1ROW);
        const short* bp = wF + (size_t)(96 + l*16 + nt*4 + kc)*512 + lane*8;
        bf16x8 B = *(const bf16x8*)(bp);
        c0 = __builtin_amdgcn_mfma_f32_16x16x32_bf16(A0, B, c0, 0,0,0);
        c1 = __builtin_amdgcn_mfma_f32_16x16x32_bf16(A1, B, c1, 0,0,0);
        c2 = __builtin_amdgcn_mfma_f32_16x16x32_bf16(A2, B, c2, 0,0,0);
        c3 = __builtin_amdgcn_mfma_f32_16x16x32_bf16(A3, B, c3, 0,0,0);
      }
      __syncthreads();
      const int c = nt*16 + n16;
      const float bias = ff2_b[l*64 + c];
      #pragma unroll
      for (int r = 0; r < 4; ++r) {
        int m0 = mrow + r;
        arena[m0*68 + c] = xf[m0*64 + c] + bias + c0[r];
        if (m0+16 < SHORTN) arena[(m0+16)*68 + c] = xf[(m0+16)*64 + c] + bias + c1[r];
        if (m0+32 < SHORTN) arena[(m0+32)*68 + c] = xf[(m0+32)*64 + c] + bias + c2[r];
        if (m0+48 < SHORTN) arena[(m0+48)*68 + c] = xf[(m0+48)*64 + c] + bias + c3[r];
      }
    }
    __syncthreads();

    // ======== LN2 ========
    {
      const float g = ln2_g[l*64 + lane], bb = ln2_b[l*64 + lane];
      for (int s = wid; s < SHORTN; s += 4) {
        float y = arena[s*68 + lane];
        float mean = wave_sum(y) * (1.f/64.f);
        float dv = y - mean;
        float var = wave_sum(dv*dv) * (1.f/64.f);
        float r = dv / sqrtf(var + 1e-5f) * g + bb;
        xf[s*64 + lane] = r;
        xbf[s*BROW + lane] = (short)f2bf(r);
      }
    }
    __syncthreads();
  }

  float acc = 0.f;
  for (int s = wid; s < SHORTN; s += 4) acc += xf[s*64 + lane];
  qf[wid*64 + lane] = acc;
  __syncthreads();
  if (wid == 0)
    bst_out[b*64 + lane] = (qf[lane] + qf[64+lane] + qf[128+lane] + qf[192+lane]) * (1.f/50.f);
}

// ===========================================================================
// K2+K4 merged: softmax(1000) + bitonic top-50 + re-softmax + hard/soft repr
// kept in LDS + fusion MLP -> final out. grid = NB.
// ===========================================================================
__global__ __launch_bounds__(256) void hard_finish_fusion_kernel(
    const int* __restrict__ long_hist_ids,
    const float* __restrict__ item_emb,
    const float* __restrict__ sdim_w, const float* __restrict__ sdim_b,
    const float* __restrict__ scores_ws,
    const float* __restrict__ partA, const float* __restrict__ partH,
    const float* __restrict__ user, const float* __restrict__ bst,
    const float* __restrict__ w1, const float* __restrict__ b1,
    const float* __restrict__ w2, const float* __restrict__ b2,
    const float* __restrict__ w3, const float* __restrict__ b3,
    float* __restrict__ out)
{
  __shared__ __align__(16) float scores[LONGN];
  __shared__ int   idsL[LONGN];
  __shared__ __align__(16) unsigned long long kv[1024];
  __shared__ __align__(16) float redE[4*64];
  __shared__ __align__(16) float vecbuf[64];
  __shared__ float redV[4];
  __shared__ float selV[TOPKN];
  __shared__ int   selI[TOPKN];
  __shared__ __align__(16) float comb[256];
  __shared__ __align__(16) float h1[256];
  __shared__ __align__(16) float h2[128];

  const int b = blockIdx.x;
  const int tid = threadIdx.x;
  const int wid = tid >> 6, lane = tid & 63;

  for (int l = tid; l < LONGN; l += 256) {
    scores[l] = scores_ws[b*LONGN + l];
    idsL[l] = long_hist_ids[b*LONGN + l];
  }
  // stage user + bst into comb while scores load
  if (tid < 64)       comb[tid] = user[b*64 + tid];
  else if (tid >= 192) comb[tid] = bst[b*64 + tid - 192];
  __syncthreads();

  // ---- soft_repr -> comb[128..192) ----
  if (tid < 64)
    vecbuf[tid] = (partA[(2*b)*64 + tid] + partA[(2*b+1)*64 + tid]
                 + partH[(2*b)*64 + tid] + partH[(2*b+1)*64 + tid]) * (1.f/1000.f);
  __syncthreads();
  if (tid < 64)
    comb[128 + tid] = sdim_b[tid] + dotN<64>(sdim_w + tid*64, vecbuf);

  // ---- softmax over 1000 ----
  float mx = -INFINITY;
  for (int l = tid; l < LONGN; l += 256) mx = fmaxf(mx, scores[l]);
  mx = wave_max(mx);
  if (lane == 0) redV[wid] = mx;
  __syncthreads();
  mx = fmaxf(fmaxf(redV[0], redV[1]), fmaxf(redV[2], redV[3]));
  __syncthreads();
  float sm = 0.f;
  for (int l = tid; l < LONGN; l += 256) {
    float a = expf(scores[l] - mx);
    scores[l] = a;
    sm += a;
  }
  sm = wave_sum(sm);
  if (lane == 0) redV[wid] = sm;
  __syncthreads();
  {
    const float inv = 1.f / (redV[0] + redV[1] + redV[2] + redV[3]);
    for (int l = tid; l < LONGN; l += 256) scores[l] *= inv;
  }
  __syncthreads();

  // ---- composite keys + bitonic sort (top-50 first, ties->smallest idx) ----
  for (int l = tid; l < 1024; l += 256) {
    if (l < LONGN) {
      unsigned vb = __float_as_uint(scores[l]);
      kv[l] = ((unsigned long long)(~vb) << 32) | (unsigned)l;
    } else {
      kv[l] = 0xFFFFFFFFFFFFFFFFull;
    }
  }
  __syncthreads();

  for (int k = 2; k <= 1024; k <<= 1) {
    for (int j = k >> 1; j > 0; j >>= 1) {
      #pragma unroll 2
      for (int p = tid; p < 512; p += 256) {
        const int i = ((p & ~(j-1)) << 1) | (p & (j-1));
        const int m = i + j;
        const bool up = ((i & k) == 0);
        unsigned long long a = kv[i], c = kv[m];
        if ((a > c) == up) { kv[i] = c; kv[m] = a; }
      }
      __syncthreads();
    }
  }

  if (tid < TOPKN) {
    unsigned long long key = kv[tid];
    selI[tid] = (int)(unsigned)(key & 0xFFFFFFFFu);
    selV[tid] = __uint_as_float(~(unsigned)(key >> 32));
  }
  __syncthreads();

  // ---- softmax over the 50 selected ----
  if (wid == 0) {
    float v = (lane < TOPKN) ? selV[lane] : -INFINITY;
    float m2 = wave_max(v);
    float e = (lane < TOPKN) ? expf(v - m2) : 0.f;
    float s2 = wave_sum(e);
    if (lane < TOPKN) selV[lane] = e / s2;
  }
  __syncthreads();

  // ---- hard_repr -> comb[64..128) ----
  float accR = 0.f;
  for (int r = wid; r < TOPKN; r += 4)
    accR += selV[r] * item_emb[idsL[selI[r]]*64 + lane];
  redE[wid*64 + lane] = accR;
  __syncthreads();
  if (wid == 0)
    comb[64 + lane] = redE[lane] + redE[64+lane] + redE[128+lane] + redE[192+lane];
  __syncthreads();

  // ---- fusion MLP ----
  h1[tid] = fmaxf(b1[tid] + dotN<256>(w1 + tid*256, comb), 0.f);
  __syncthreads();
  if (tid < 128) h2[tid] = fmaxf(b2[tid] + dotN<256>(w2 + tid*256, h1), 0.f);
  __syncthreads();
  if (tid < 64) {
    float p = w3[tid]*h2[tid] + w3[tid+64]*h2[tid+64];
    p = wave_sum(p);
    if (tid == 0) out[b] = p + b3[0];
  }
}

extern "C" void kernel_launch(void* const* d_in, const int* in_sizes, int n_in,
                              void* d_out, int out_size, void* d_ws, size_t ws_size,
                              hipStream_t stream) {
  const float* user_features  = (const float*)d_in[0];
  const int*   target_item_id = (const int*)  d_in[1];
  const int*   short_hist_ids = (const int*)  d_in[2];
  const int*   long_hist_ids  = (const int*)  d_in[3];
  const float* item_emb       = (const float*)d_in[4];
  const float* tproj_w  = (const float*)d_in[5];
  const float* tproj_b  = (const float*)d_in[6];
  const float* attn_w1  = (const float*)d_in[7];
  const float* attn_b1  = (const float*)d_in[8];
  const float* attn_w2  = (const float*)d_in[9];
  const float* attn_b2  = (const float*)d_in[10];
  const float* hash_emb = (const float*)d_in[11];
  const float* sdim_w   = (const float*)d_in[12];
  const float* sdim_b   = (const float*)d_in[13];
  const float* tf_qkv_w = (const float*)d_in[14];
  const float* tf_qkv_b = (const float*)d_in[15];
  const float* tf_out_w = (const float*)d_in[16];
  const float* tf_out_b = (const float*)d_in[17];
  const float* tf_ln1_g = (const float*)d_in[18];
  const float* tf_ln1_b = (const float*)d_in[19];
  const float* tf_ff1_w = (const float*)d_in[20];
  const float* tf_ff1_b = (const float*)d_in[21];
  const float* tf_ff2_w = (const float*)d_in[22];
  const float* tf_ff2_b = (const float*)d_in[23];
  const float* tf_ln2_g = (const float*)d_in[24];
  const float* tf_ln2_b = (const float*)d_in[25];
  const float* fus_w1   = (const float*)d_in[26];
  const float* fus_b1   = (const float*)d_in[27];
  const float* fus_w2   = (const float*)d_in[28];
  const float* fus_b2   = (const float*)d_in[29];
  const float* fus_w3   = (const float*)d_in[30];
  const float* fus_b3   = (const float*)d_in[31];

  float* ws = (float*)d_ws;
  float* hard = ws;                    // NB*64 (unused, kept for layout)
  float* soft = hard + NB*64;          // NB*64 (unused)
  float* bst  = soft + NB*64;          // NB*64
  float* scores_ws = bst + NB*64;      // NB*1000
  float* partA = scores_ws + NB*LONGN; // NB*2*64
  float* partH = partA + NB*2*64;      // NB*2*64
  short* wF    = (short*)(partH + NB*2*64); // 65536 shorts (128 KB)

  bst_prep_kernel<<<32, 256, 0, stream>>>(tf_qkv_w, tf_out_w, tf_ff1_w, tf_ff2_w, wF);
  hard_scores_kernel<<<2*NB, 256, 0, stream>>>(target_item_id, long_hist_ids,
      item_emb, tproj_w, tproj_b, attn_w1, attn_b1, attn_w2, attn_b2,
      hash_emb, scores_ws, partA, partH);
  bst_kernel<<<NB, 256, 0, stream>>>(short_hist_ids, item_emb, wF,
      tf_qkv_b, tf_out_b, tf_ln1_g, tf_ln1_b, tf_ff1_b, tf_ff2_b,
      tf_ln2_g, tf_ln2_b, bst);
  hard_finish_fusion_kernel<<<NB, 256, 0, stream>>>(long_hist_ids, item_emb,
      sdim_w, sdim_b, scores_ws, partA, partH,
      user_features, bst, fus_w1, fus_b1, fus_w2, fus_b2, fus_w3, fus_b3,
      (float*)d_out);
}